// Round 1
// baseline (9386.742 us; speedup 1.0000x reference)
//
#include <hip/hip_runtime.h>

#define N_NODES 50000
#define N_EDGES 600000
#define D 128

// --- degree counting: deg_out[src]++, deg_in[dst]++ (exact in fp32, counts << 2^24)
__global__ void deg_kernel(const int* __restrict__ src, const int* __restrict__ dst,
                           float* __restrict__ degO, float* __restrict__ degI, int nEdges) {
    int e = blockIdx.x * blockDim.x + threadIdx.x;
    if (e < nEdges) {
        atomicAdd(&degO[src[e]], 1.0f);
        atomicAdd(&degI[dst[e]], 1.0f);
    }
}

// --- in-place deg -> rsqrt(max(deg,1))
__global__ void rsqrt_kernel(float* __restrict__ degO, float* __restrict__ degI, int n) {
    int i = blockIdx.x * blockDim.x + threadIdx.x;
    if (i < n) {
        degO[i] = 1.0f / sqrtf(fmaxf(degO[i], 1.0f));
        degI[i] = 1.0f / sqrtf(fmaxf(degI[i], 1.0f));
    }
}

// --- A[i][:] = x[i][:] * rs[i]   (vectorized float4; n = N_NODES*32 float4s)
__global__ void scale_kernel(const float4* __restrict__ x, const float* __restrict__ rs,
                             float4* __restrict__ out, int n) {
    int i = blockIdx.x * blockDim.x + threadIdx.x;
    if (i < n) {
        float s = rs[i >> 5];          // 32 float4 per 128-wide row
        float4 v = x[i];
        v.x *= s; v.y *= s; v.z *= s; v.w *= s;
        out[i] = v;
    }
}

// --- SpMM: B[dst[e]][:] += A[src[e]][:]  (32 threads per edge, float4 each)
__global__ void spmm_kernel(const int* __restrict__ src, const int* __restrict__ dst,
                            const float4* __restrict__ h, float* __restrict__ agg, int nEdges) {
    int gid = blockIdx.x * blockDim.x + threadIdx.x;
    int e = gid >> 5;
    int q = gid & 31;
    if (e < nEdges) {
        int s = src[e];
        int d = dst[e];
        float4 v = h[s * 32 + q];
        float* ap = agg + d * 128 + q * 4;
        atomicAdd(ap + 0, v.x);
        atomicAdd(ap + 1, v.y);
        atomicAdd(ap + 2, v.z);
        atomicAdd(ap + 3, v.w);
    }
}

// --- GEMM: per row r: o[c] = relu( rsI[r] * sum_k agg[r][k]*W[k][c] + b[c] )
//     FUSE==0: write out[r][c] = o[c] * rsO[r]   (pre-scale for next layer's SpMM)
//     FUSE==1: accumulate sum(o) into double *acc (final reduction)
template <int FUSE>
__global__ __launch_bounds__(256) void gemm_kernel(
        const float* __restrict__ agg, const float* __restrict__ rsI,
        const float* __restrict__ rsO,
        const float* __restrict__ W, const float* __restrict__ b,
        float* __restrict__ out, double* __restrict__ acc, int nNodes) {
    __shared__ float Wl[128][128];     // 64 KiB (gfx950 allows up to 160 KiB/WG)
    __shared__ float rowbuf[2][128];   // 1 KiB
    __shared__ double wred[4];

    for (int i = threadIdx.x; i < 128 * 128; i += 256)
        Wl[i >> 7][i & 127] = W[i];
    __syncthreads();

    const int c = threadIdx.x & 127;
    const int half = threadIdx.x >> 7;
    const float bc = b[c];
    double lsum = 0.0;

    for (int r0 = blockIdx.x * 2; r0 < nNodes; r0 += gridDim.x * 2) {
        {   // stage 2 rows, pre-scaled by rsI
            int idx = threadIdx.x;
            int rr = r0 + (idx >> 7);
            float v = 0.0f;
            if (rr < nNodes) v = agg[rr * 128 + (idx & 127)] * rsI[rr];
            rowbuf[idx >> 7][idx & 127] = v;
        }
        __syncthreads();

        int r = r0 + half;
        float a0 = 0.f, a1 = 0.f, a2 = 0.f, a3 = 0.f;
        #pragma unroll
        for (int k = 0; k < 128; k += 4) {
            a0 = fmaf(rowbuf[half][k + 0], Wl[k + 0][c], a0);
            a1 = fmaf(rowbuf[half][k + 1], Wl[k + 1][c], a1);
            a2 = fmaf(rowbuf[half][k + 2], Wl[k + 2][c], a2);
            a3 = fmaf(rowbuf[half][k + 3], Wl[k + 3][c], a3);
        }
        float o = fmaxf((a0 + a1) + (a2 + a3) + bc, 0.0f);
        if (r < nNodes) {
            if (FUSE) lsum += (double)o;
            else out[r * 128 + c] = o * rsO[r];
        }
        __syncthreads();
    }

    if (FUSE) {
        for (int off = 32; off; off >>= 1) lsum += __shfl_down(lsum, off, 64);
        if ((threadIdx.x & 63) == 0) wred[threadIdx.x >> 6] = lsum;
        __syncthreads();
        if (threadIdx.x == 0) atomicAdd(acc, wred[0] + wred[1] + wred[2] + wred[3]);
    }
}

__global__ void finalize_kernel(const double* __restrict__ acc, float* __restrict__ out) {
    if (threadIdx.x == 0 && blockIdx.x == 0)
        out[0] = (float)(acc[0] / (4.0 * N_NODES * D));
}

extern "C" void kernel_launch(void* const* d_in, const int* in_sizes, int n_in,
                              void* d_out, int out_size, void* d_ws, size_t ws_size,
                              hipStream_t stream) {
    const float* x[4];
    const int* src[4];
    const int* dst[4];
    for (int g = 0; g < 4; ++g) {
        x[g]   = (const float*)d_in[3 * g + 0];
        src[g] = (const int*)  d_in[3 * g + 1];
        dst[g] = (const int*)  d_in[3 * g + 2];
    }
    const float* W1 = (const float*)d_in[12];
    const float* b1 = (const float*)d_in[13];
    const float* W2 = (const float*)d_in[14];
    const float* b2 = (const float*)d_in[15];
    float* out = (float*)d_out;

    // workspace layout
    char* ws = (char*)d_ws;
    double* acc = (double*)ws;                       // 8 B (padded to 256)
    float* rsO = (float*)(ws + 256);                 // N floats
    float* rsI = rsO + N_NODES;                      // N floats (contiguous with rsO)
    float* A   = rsI + N_NODES;                      // N*128 floats
    float* B   = A + (size_t)N_NODES * D;            // N*128 floats
    // total: 256 + 400000 + 2*25.6e6 B ~= 51.6 MiB

    hipMemsetAsync(acc, 0, sizeof(double), stream);

    const int degGrid  = (N_EDGES + 255) / 256;
    const int nodeGrid = (N_NODES + 255) / 256;
    const int scaleN   = N_NODES * 32;
    const int scaleGrid = (scaleN + 255) / 256;
    const int spmmGrid = (N_EDGES * 32) / 256;       // 75000 exactly

    for (int g = 0; g < 4; ++g) {
        // degrees -> rsqrt norms
        hipMemsetAsync(rsO, 0, 2 * N_NODES * sizeof(float), stream);
        deg_kernel<<<degGrid, 256, 0, stream>>>(src[g], dst[g], rsO, rsI, N_EDGES);
        rsqrt_kernel<<<nodeGrid, 256, 0, stream>>>(rsO, rsI, N_NODES);

        // layer 1: A = x*rsO ; B = SpMM(A) ; A = relu(rsI*B@W1 + b1)*rsO
        scale_kernel<<<scaleGrid, 256, 0, stream>>>((const float4*)x[g], rsO, (float4*)A, scaleN);
        hipMemsetAsync(B, 0, (size_t)N_NODES * D * sizeof(float), stream);
        spmm_kernel<<<spmmGrid, 256, 0, stream>>>(src[g], dst[g], (const float4*)A, B, N_EDGES);
        gemm_kernel<0><<<512, 256, 0, stream>>>(B, rsI, rsO, W1, b1, A, nullptr, N_NODES);

        // layer 2: B = SpMM(A) ; acc += sum(relu(rsI*B@W2 + b2))
        hipMemsetAsync(B, 0, (size_t)N_NODES * D * sizeof(float), stream);
        spmm_kernel<<<spmmGrid, 256, 0, stream>>>(src[g], dst[g], (const float4*)A, B, N_EDGES);
        gemm_kernel<1><<<512, 256, 0, stream>>>(B, rsI, rsO, W2, b2, nullptr, acc, N_NODES);
    }

    finalize_kernel<<<1, 64, 0, stream>>>(acc, out);
}

// Round 2
// 1165.284 us; speedup vs baseline: 8.0553x; 8.0553x over previous
//
#include <hip/hip_runtime.h>

#define N_NODES 50000
#define N_EDGES 600000
#define D 128

#define SCAN_BLOCK 256
#define SCAN_ELEMS 8
#define SCAN_PER_BLOCK (SCAN_BLOCK * SCAN_ELEMS)          // 2048
#define SCAN_NBLOCKS ((N_NODES + SCAN_PER_BLOCK - 1) / SCAN_PER_BLOCK)  // 25

// --- histogram: cntI[dst]++, cntO[src]++ (int atomics)
__global__ void hist_kernel(const int* __restrict__ src, const int* __restrict__ dst,
                            int* __restrict__ cntI, int* __restrict__ cntO, int nEdges) {
    int e = blockIdx.x * blockDim.x + threadIdx.x;
    if (e < nEdges) {
        atomicAdd(&cntI[dst[e]], 1);
        atomicAdd(&cntO[src[e]], 1);
    }
}

// --- scan phase A: per-block sums of cntI
__global__ __launch_bounds__(SCAN_BLOCK) void scanA_kernel(
        const int* __restrict__ cntI, int* __restrict__ blockSums) {
    int t = threadIdx.x, b = blockIdx.x;
    int base = b * SCAN_PER_BLOCK + t * SCAN_ELEMS;
    int s = 0;
    #pragma unroll
    for (int j = 0; j < SCAN_ELEMS; ++j) {
        int i = base + j;
        if (i < N_NODES) s += cntI[i];
    }
    // wave reduce
    for (int off = 32; off; off >>= 1) s += __shfl_down(s, off, 64);
    __shared__ int wsum[SCAN_BLOCK / 64];
    if ((t & 63) == 0) wsum[t >> 6] = s;
    __syncthreads();
    if (t == 0) {
        int r = 0;
        #pragma unroll
        for (int w = 0; w < SCAN_BLOCK / 64; ++w) r += wsum[w];
        blockSums[b] = r;
    }
}

// --- scan phase B: exclusive scan of block sums (single thread, 25 elems)
__global__ void scanB_kernel(int* __restrict__ blockSums, int* __restrict__ blockOffs, int nb) {
    if (threadIdx.x == 0 && blockIdx.x == 0) {
        int r = 0;
        for (int i = 0; i < nb; ++i) { blockOffs[i] = r; r += blockSums[i]; }
    }
}

// --- scan phase C: write rowptr (exclusive prefix), cursor copy, and rsqrt norms
__global__ __launch_bounds__(SCAN_BLOCK) void scanC_kernel(
        const int* __restrict__ cntI, const int* __restrict__ cntO,
        const int* __restrict__ blockOffs,
        int* __restrict__ rowptr, int* __restrict__ cursor,
        float* __restrict__ rsI, float* __restrict__ rsO) {
    int t = threadIdx.x, b = blockIdx.x;
    int base = b * SCAN_PER_BLOCK + t * SCAN_ELEMS;
    int local[SCAN_ELEMS];
    int s = 0;
    #pragma unroll
    for (int j = 0; j < SCAN_ELEMS; ++j) {
        int i = base + j;
        local[j] = (i < N_NODES) ? cntI[i] : 0;
        s += local[j];
    }
    // wave inclusive scan
    int lane = t & 63, w = t >> 6;
    int v = s;
    for (int off = 1; off < 64; off <<= 1) {
        int u = __shfl_up(v, off, 64);
        if (lane >= off) v += u;
    }
    __shared__ int wsum[SCAN_BLOCK / 64];
    if (lane == 63) wsum[w] = v;
    __syncthreads();
    if (t == 0) {
        int r = 0;
        #pragma unroll
        for (int i = 0; i < SCAN_BLOCK / 64; ++i) { int x = wsum[i]; wsum[i] = r; r += x; }
    }
    __syncthreads();
    int running = blockOffs[b] + wsum[w] + (v - s);
    #pragma unroll
    for (int j = 0; j < SCAN_ELEMS; ++j) {
        int i = base + j;
        if (i < N_NODES) {
            rowptr[i] = running;
            cursor[i] = running;
            running += local[j];
            rsI[i] = 1.0f / sqrtf(fmaxf((float)local[j], 1.0f));
            rsO[i] = 1.0f / sqrtf(fmaxf((float)cntO[i], 1.0f));
        }
    }
    if (b == SCAN_NBLOCKS - 1 && t == SCAN_BLOCK - 1)
        rowptr[N_NODES] = N_EDGES;
}

// --- scatter: bucket edge sources by dst
__global__ void scatter_kernel(const int* __restrict__ src, const int* __restrict__ dst,
                               int* __restrict__ cursor, int* __restrict__ eidx, int nEdges) {
    int e = blockIdx.x * blockDim.x + threadIdx.x;
    if (e < nEdges) {
        int p = atomicAdd(&cursor[dst[e]], 1);
        eidx[p] = src[e];
    }
}

// --- gather SpMM: out[r][:] = sum_{p in row r} h[eidx[p]][:] (* rs[eidx[p]] if SCALE)
template <int SCALE>
__global__ __launch_bounds__(256) void gather_kernel(
        const int* __restrict__ rowptr, const int* __restrict__ eidx,
        const float4* __restrict__ h, const float* __restrict__ rs,
        float4* __restrict__ out, int nNodes) {
    int gid = blockIdx.x * blockDim.x + threadIdx.x;
    int r = gid >> 5;
    int q = gid & 31;
    if (r >= nNodes) return;
    int beg = rowptr[r], end = rowptr[r + 1];
    float4 acc = make_float4(0.f, 0.f, 0.f, 0.f);
    for (int p = beg; p < end; ++p) {
        int s = eidx[p];
        float4 v = h[s * 32 + q];
        if (SCALE) {
            float sc = rs[s];
            acc.x = fmaf(v.x, sc, acc.x);
            acc.y = fmaf(v.y, sc, acc.y);
            acc.z = fmaf(v.z, sc, acc.z);
            acc.w = fmaf(v.w, sc, acc.w);
        } else {
            acc.x += v.x; acc.y += v.y; acc.z += v.z; acc.w += v.w;
        }
    }
    out[r * 32 + q] = acc;
}

// --- GEMM with 4x4 register tiling: tile = 32 rows x 128 cols per block.
// o[c] = relu( rsI[r]*sum_k agg[r][k]*W[k][c] + b[c] )
// FUSE==0: out[r][c] = o * rsO[r];  FUSE==1: acc += sum(o)
template <int FUSE>
__global__ __launch_bounds__(256) void gemm_kernel(
        const float* __restrict__ agg, const float* __restrict__ rsI,
        const float* __restrict__ rsO,
        const float* __restrict__ W, const float* __restrict__ b,
        float* __restrict__ out, double* __restrict__ acc, int nNodes) {
    __shared__ float Wl[128][128];     // 64 KiB, [k][c] row-major like W
    __shared__ float Rbuf[32][128];    // 16 KiB, rows pre-scaled by rsI
    const int t = threadIdx.x;
    const int row0 = blockIdx.x * 32;

    {   // stage W
        const float4* W4 = (const float4*)W;
        float4* Wl4 = (float4*)&Wl[0][0];
        #pragma unroll
        for (int it = 0; it < 16; ++it)
            Wl4[t + it * 256] = W4[t + it * 256];
    }
    {   // stage 32 rows, scaled by rsI
        const float4* agg4 = (const float4*)agg;
        float4* R4 = (float4*)&Rbuf[0][0];
        #pragma unroll
        for (int it = 0; it < 4; ++it) {
            int j = t + it * 256;          // 0..1023
            int row = j >> 5, q = j & 31;
            int r = row0 + row;
            float4 v = make_float4(0.f, 0.f, 0.f, 0.f);
            if (r < nNodes) {
                v = agg4[(size_t)r * 32 + q];
                float sc = rsI[r];
                v.x *= sc; v.y *= sc; v.z *= sc; v.w *= sc;
            }
            R4[j] = v;
        }
    }
    __syncthreads();

    const int c0 = (t & 31) * 4;
    const int r0 = (t >> 5) * 4;
    float accr[4][4];
    #pragma unroll
    for (int i = 0; i < 4; ++i)
        #pragma unroll
        for (int j = 0; j < 4; ++j) accr[i][j] = 0.f;

    #pragma unroll 8
    for (int k = 0; k < 128; ++k) {
        float4 wv = *(const float4*)&Wl[k][c0];
        float a0 = Rbuf[r0 + 0][k];
        float a1 = Rbuf[r0 + 1][k];
        float a2 = Rbuf[r0 + 2][k];
        float a3 = Rbuf[r0 + 3][k];
        accr[0][0] = fmaf(a0, wv.x, accr[0][0]);
        accr[0][1] = fmaf(a0, wv.y, accr[0][1]);
        accr[0][2] = fmaf(a0, wv.z, accr[0][2]);
        accr[0][3] = fmaf(a0, wv.w, accr[0][3]);
        accr[1][0] = fmaf(a1, wv.x, accr[1][0]);
        accr[1][1] = fmaf(a1, wv.y, accr[1][1]);
        accr[1][2] = fmaf(a1, wv.z, accr[1][2]);
        accr[1][3] = fmaf(a1, wv.w, accr[1][3]);
        accr[2][0] = fmaf(a2, wv.x, accr[2][0]);
        accr[2][1] = fmaf(a2, wv.y, accr[2][1]);
        accr[2][2] = fmaf(a2, wv.z, accr[2][2]);
        accr[2][3] = fmaf(a2, wv.w, accr[2][3]);
        accr[3][0] = fmaf(a3, wv.x, accr[3][0]);
        accr[3][1] = fmaf(a3, wv.y, accr[3][1]);
        accr[3][2] = fmaf(a3, wv.z, accr[3][2]);
        accr[3][3] = fmaf(a3, wv.w, accr[3][3]);
    }

    const float4 bv = *(const float4*)&b[c0];
    double lsum = 0.0;
    #pragma unroll
    for (int i = 0; i < 4; ++i) {
        int r = row0 + r0 + i;
        if (r < nNodes) {
            float o0 = fmaxf(accr[i][0] + bv.x, 0.f);
            float o1 = fmaxf(accr[i][1] + bv.y, 0.f);
            float o2 = fmaxf(accr[i][2] + bv.z, 0.f);
            float o3 = fmaxf(accr[i][3] + bv.w, 0.f);
            if (FUSE) {
                lsum += (double)o0 + (double)o1 + (double)o2 + (double)o3;
            } else {
                float sc = rsO[r];
                float4 ov = make_float4(o0 * sc, o1 * sc, o2 * sc, o3 * sc);
                *(float4*)&out[(size_t)r * 128 + c0] = ov;
            }
        }
    }

    if (FUSE) {
        for (int off = 32; off; off >>= 1) lsum += __shfl_down(lsum, off, 64);
        __shared__ double wred[4];
        if ((t & 63) == 0) wred[t >> 6] = lsum;
        __syncthreads();
        if (t == 0) atomicAdd(acc, wred[0] + wred[1] + wred[2] + wred[3]);
    }
}

__global__ void finalize_kernel(const double* __restrict__ acc, float* __restrict__ out) {
    if (threadIdx.x == 0 && blockIdx.x == 0)
        out[0] = (float)(acc[0] / (4.0 * N_NODES * D));
}

extern "C" void kernel_launch(void* const* d_in, const int* in_sizes, int n_in,
                              void* d_out, int out_size, void* d_ws, size_t ws_size,
                              hipStream_t stream) {
    const float* x[4];
    const int* src[4];
    const int* dst[4];
    for (int g = 0; g < 4; ++g) {
        x[g]   = (const float*)d_in[3 * g + 0];
        src[g] = (const int*)  d_in[3 * g + 1];
        dst[g] = (const int*)  d_in[3 * g + 2];
    }
    const float* W1 = (const float*)d_in[12];
    const float* b1 = (const float*)d_in[13];
    const float* W2 = (const float*)d_in[14];
    const float* b2 = (const float*)d_in[15];
    float* out = (float*)d_out;

    // workspace layout
    char* ws = (char*)d_ws;
    double* acc    = (double*)ws;                          // 256 B slot
    int* blockSums = (int*)(ws + 256);                     // 25 ints (pad to 128)
    int* blockOffs = blockSums + 32;                       // 25 ints
    float* rsO = (float*)(ws + 512);                       // N
    float* rsI = rsO + N_NODES;                            // N
    int* cntI  = (int*)(rsI + N_NODES);                    // N+1 (doubles as rowptr)
    int* rowptr = cntI;                                    // in-place: scanC reads cnt, writes ptr
    int* cntO  = cntI + N_NODES + 1;                       // N (doubles as cursor)
    int* cursor = cntO;
    int* eidx  = cntO + N_NODES;                           // E
    float* A   = (float*)(eidx + N_EDGES);                 // N*128
    float* B   = A + (size_t)N_NODES * D;                  // N*128
    // total ~ 54.4 MB

    hipMemsetAsync(acc, 0, sizeof(double), stream);

    const int eGrid = (N_EDGES + 255) / 256;
    const int gatherGrid = (N_NODES * 32) / 256 + 1;       // 6251
    const int gemmGrid = (N_NODES + 31) / 32;              // 1563

    for (int g = 0; g < 4; ++g) {
        // CSR build + norms
        hipMemsetAsync(cntI, 0, (2 * N_NODES + 1) * sizeof(int), stream);
        hist_kernel<<<eGrid, 256, 0, stream>>>(src[g], dst[g], cntI, cntO, N_EDGES);
        scanA_kernel<<<SCAN_NBLOCKS, SCAN_BLOCK, 0, stream>>>(cntI, blockSums);
        scanB_kernel<<<1, 64, 0, stream>>>(blockSums, blockOffs, SCAN_NBLOCKS);
        scanC_kernel<<<SCAN_NBLOCKS, SCAN_BLOCK, 0, stream>>>(
            cntI, cntO, blockOffs, rowptr, cursor, rsI, rsO);
        scatter_kernel<<<eGrid, 256, 0, stream>>>(src[g], dst[g], cursor, eidx, N_EDGES);

        // layer 1: B = SpMM(x * rsO) ; A = relu(rsI*B@W1 + b1) * rsO
        gather_kernel<1><<<gatherGrid, 256, 0, stream>>>(
            rowptr, eidx, (const float4*)x[g], rsO, (float4*)B, N_NODES);
        gemm_kernel<0><<<gemmGrid, 256, 0, stream>>>(B, rsI, rsO, W1, b1, A, nullptr, N_NODES);

        // layer 2: B = SpMM(A) ; acc += sum(relu(rsI*B@W2 + b2))
        gather_kernel<0><<<gatherGrid, 256, 0, stream>>>(
            rowptr, eidx, (const float4*)A, nullptr, (float4*)B, N_NODES);
        gemm_kernel<1><<<gemmGrid, 256, 0, stream>>>(B, rsI, rsO, W2, b2, nullptr, acc, N_NODES);
    }

    finalize_kernel<<<1, 64, 0, stream>>>(acc, out);
}

// Round 3
// 1085.231 us; speedup vs baseline: 8.6495x; 1.0738x over previous
//
#include <hip/hip_runtime.h>

#define N_NODES 50000
#define N_EDGES 600000
#define D 128

#define SCAN_BLOCK 256
#define SCAN_ELEMS 8
#define SCAN_PER_BLOCK (SCAN_BLOCK * SCAN_ELEMS)          // 2048
#define SCAN_NBLOCKS ((N_NODES + SCAN_PER_BLOCK - 1) / SCAN_PER_BLOCK)  // 25

#define CPG 100032   // per-graph counter region: cntI(N+1) + cntO(N), padded (ints)

__device__ __forceinline__ const int* pick4(const int* a, const int* b,
                                            const int* c, const int* d, int g) {
    return g == 0 ? a : g == 1 ? b : g == 2 ? c : d;
}

// --- histogram: cntI[dst]++, cntO[src]++  (graph = gFirst + blockIdx.y)
__global__ void hist_kernel(const int* s0, const int* s1, const int* s2, const int* s3,
                            const int* d0, const int* d1, const int* d2, const int* d3,
                            int* __restrict__ cntBase, int gFirst, int nEdges) {
    int gi = blockIdx.y;
    const int* src = pick4(s0, s1, s2, s3, gFirst + gi);
    const int* dst = pick4(d0, d1, d2, d3, gFirst + gi);
    int* cntI = cntBase + (size_t)gi * CPG;
    int* cntO = cntI + (N_NODES + 1);
    int e = blockIdx.x * blockDim.x + threadIdx.x;
    if (e < nEdges) {
        atomicAdd(&cntI[dst[e]], 1);
        atomicAdd(&cntO[src[e]], 1);
    }
}

// --- scan phase A: per-block sums of cntI
__global__ __launch_bounds__(SCAN_BLOCK) void scanA_kernel(
        const int* __restrict__ cntBase, int* __restrict__ blockSums) {
    int gi = blockIdx.y;
    const int* cntI = cntBase + (size_t)gi * CPG;
    int t = threadIdx.x, bk = blockIdx.x;
    int base = bk * SCAN_PER_BLOCK + t * SCAN_ELEMS;
    int s = 0;
    #pragma unroll
    for (int j = 0; j < SCAN_ELEMS; ++j) {
        int i = base + j;
        if (i < N_NODES) s += cntI[i];
    }
    for (int off = 32; off; off >>= 1) s += __shfl_down(s, off, 64);
    __shared__ int wsum[SCAN_BLOCK / 64];
    if ((t & 63) == 0) wsum[t >> 6] = s;
    __syncthreads();
    if (t == 0) {
        int r = 0;
        #pragma unroll
        for (int w = 0; w < SCAN_BLOCK / 64; ++w) r += wsum[w];
        blockSums[gi * 32 + bk] = r;
    }
}

// --- scan phase C (with inline scan of the 25 block sums): rowptr (in place over
//     cntI), cursor copy, rsqrt norms.
__global__ __launch_bounds__(SCAN_BLOCK) void scanC_kernel(
        int* __restrict__ cntBase, const int* __restrict__ blockSums,
        int* __restrict__ curBase, float* __restrict__ rsIBase,
        float* __restrict__ rsOBase) {
    int gi = blockIdx.y;
    int* cntI = cntBase + (size_t)gi * CPG;        // becomes rowptr in place
    const int* cntO = cntI + (N_NODES + 1);
    int* rowptr = cntI;
    int* cursor = curBase + (size_t)gi * N_NODES;
    float* rsI = rsIBase + (size_t)gi * N_NODES;
    float* rsO = rsOBase + (size_t)gi * N_NODES;

    int t = threadIdx.x, bk = blockIdx.x;

    __shared__ int boffs[SCAN_NBLOCKS];
    if (t == 0) {
        int r = 0;
        for (int i = 0; i < SCAN_NBLOCKS; ++i) { boffs[i] = r; r += blockSums[gi * 32 + i]; }
    }

    int base = bk * SCAN_PER_BLOCK + t * SCAN_ELEMS;
    int local[SCAN_ELEMS];
    int s = 0;
    #pragma unroll
    for (int j = 0; j < SCAN_ELEMS; ++j) {
        int i = base + j;
        local[j] = (i < N_NODES) ? cntI[i] : 0;
        s += local[j];
    }
    // wave inclusive scan
    int lane = t & 63, w = t >> 6;
    int v = s;
    for (int off = 1; off < 64; off <<= 1) {
        int u = __shfl_up(v, off, 64);
        if (lane >= off) v += u;
    }
    __shared__ int wsum[SCAN_BLOCK / 64];
    if (lane == 63) wsum[w] = v;
    __syncthreads();
    if (t == 0) {
        int r = 0;
        #pragma unroll
        for (int i = 0; i < SCAN_BLOCK / 64; ++i) { int x = wsum[i]; wsum[i] = r; r += x; }
    }
    __syncthreads();
    int running = boffs[bk] + wsum[w] + (v - s);
    #pragma unroll
    for (int j = 0; j < SCAN_ELEMS; ++j) {
        int i = base + j;
        if (i < N_NODES) {
            rowptr[i] = running;
            cursor[i] = running;
            running += local[j];
            rsI[i] = 1.0f / sqrtf(fmaxf((float)local[j], 1.0f));
            rsO[i] = 1.0f / sqrtf(fmaxf((float)cntO[i], 1.0f));
        }
    }
    if (bk == SCAN_NBLOCKS - 1 && t == SCAN_BLOCK - 1)
        rowptr[N_NODES] = N_EDGES;
}

// --- scatter: bucket edge sources by dst
__global__ void scatter_kernel(const int* s0, const int* s1, const int* s2, const int* s3,
                               const int* d0, const int* d1, const int* d2, const int* d3,
                               int* __restrict__ curBase, int* __restrict__ eixBase,
                               int gFirst, int nEdges) {
    int gi = blockIdx.y;
    const int* src = pick4(s0, s1, s2, s3, gFirst + gi);
    const int* dst = pick4(d0, d1, d2, d3, gFirst + gi);
    int* cursor = curBase + (size_t)gi * N_NODES;
    int* eidx = eixBase + (size_t)gi * N_EDGES;
    int e = blockIdx.x * blockDim.x + threadIdx.x;
    if (e < nEdges) {
        int p = atomicAdd(&cursor[dst[e]], 1);
        eidx[p] = src[e];
    }
}

// --- gather SpMM: out[r][:] = sum_{p in row r} h[eidx[p]][:] (* rs[eidx[p]] if SCALE)
template <int SCALE>
__global__ __launch_bounds__(256) void gather_kernel(
        const int* __restrict__ rowptr, const int* __restrict__ eidx,
        const float4* __restrict__ h, const float* __restrict__ rs,
        float4* __restrict__ out, int nNodes) {
    int gid = blockIdx.x * blockDim.x + threadIdx.x;
    int r = gid >> 5;
    int q = gid & 31;
    if (r >= nNodes) return;
    int p = rowptr[r], end = rowptr[r + 1];
    float4 accA = make_float4(0.f, 0.f, 0.f, 0.f);
    float4 accB = make_float4(0.f, 0.f, 0.f, 0.f);
    for (; p + 2 <= end; p += 2) {
        int s0 = eidx[p], s1 = eidx[p + 1];
        float4 v0 = h[s0 * 32 + q];
        float4 v1 = h[s1 * 32 + q];
        if (SCALE) {
            float c0 = rs[s0], c1 = rs[s1];
            accA.x = fmaf(v0.x, c0, accA.x); accA.y = fmaf(v0.y, c0, accA.y);
            accA.z = fmaf(v0.z, c0, accA.z); accA.w = fmaf(v0.w, c0, accA.w);
            accB.x = fmaf(v1.x, c1, accB.x); accB.y = fmaf(v1.y, c1, accB.y);
            accB.z = fmaf(v1.z, c1, accB.z); accB.w = fmaf(v1.w, c1, accB.w);
        } else {
            accA.x += v0.x; accA.y += v0.y; accA.z += v0.z; accA.w += v0.w;
            accB.x += v1.x; accB.y += v1.y; accB.z += v1.z; accB.w += v1.w;
        }
    }
    if (p < end) {
        int s0 = eidx[p];
        float4 v0 = h[s0 * 32 + q];
        float c0 = SCALE ? rs[s0] : 1.0f;
        accA.x = fmaf(v0.x, c0, accA.x); accA.y = fmaf(v0.y, c0, accA.y);
        accA.z = fmaf(v0.z, c0, accA.z); accA.w = fmaf(v0.w, c0, accA.w);
    }
    accA.x += accB.x; accA.y += accB.y; accA.z += accB.z; accA.w += accB.w;
    out[r * 32 + q] = accA;
}

// --- persistent GEMM: W staged once/block, double-buffered 64-row chunks,
//     thread tile 4 rows x 8 cols. o = relu(rsI[r]*(agg[r]@W) + b)
//     FUSE==0: out[r][c] = o * rsO[r];  FUSE==1: acc += sum(o)
#define ROW_FMA(i, av)                                         \
    accr[i][0] = fmaf(av, wA.x, accr[i][0]);                   \
    accr[i][1] = fmaf(av, wA.y, accr[i][1]);                   \
    accr[i][2] = fmaf(av, wA.z, accr[i][2]);                   \
    accr[i][3] = fmaf(av, wA.w, accr[i][3]);                   \
    accr[i][4] = fmaf(av, wB.x, accr[i][4]);                   \
    accr[i][5] = fmaf(av, wB.y, accr[i][5]);                   \
    accr[i][6] = fmaf(av, wB.z, accr[i][6]);                   \
    accr[i][7] = fmaf(av, wB.w, accr[i][7]);

#define KK_STEP(kk, v0, v1, v2, v3)                            \
    {                                                          \
        const float4 wA = *(const float4*)&Wl[k + kk][c0];     \
        const float4 wB = *(const float4*)&Wl[k + kk][c0 + 4]; \
        ROW_FMA(0, v0) ROW_FMA(1, v1)                          \
        ROW_FMA(2, v2) ROW_FMA(3, v3)                          \
    }

template <int FUSE>
__global__ __launch_bounds__(256) void gemm_kernel(
        const float* __restrict__ agg, const float* __restrict__ rsI,
        const float* __restrict__ rsO,
        const float* __restrict__ W, const float* __restrict__ b,
        float* __restrict__ out, double* __restrict__ acc, int nNodes) {
    __shared__ float Wl[128][128];       // 64 KiB, [k][c]
    __shared__ float Rb[2][64][136];     // 68 KiB, padded stride (bank-spread rows)
    const int t = threadIdx.x;

    {   // stage W once
        const float4* W4 = (const float4*)W;
        float4* Wl4 = (float4*)&Wl[0][0];
        #pragma unroll
        for (int it = 0; it < 16; ++it)
            Wl4[t + it * 256] = W4[t + it * 256];
    }

    const int cg = t & 15;               // 16 col groups
    const int rg4 = (t >> 4) * 4;        // 16 row groups x 4 rows
    const int c0 = cg * 8;
    const int nChunks = (nNodes + 63) >> 6;

    const float4* b4 = (const float4*)b;
    const float4 bA = b4[cg * 2];
    const float4 bB = b4[cg * 2 + 1];

    auto stage = [&](int buf, int chunk) {
        const float4* agg4 = (const float4*)agg;
        #pragma unroll
        for (int it = 0; it < 8; ++it) {
            int j = t + it * 256;            // 0..2047
            int row = j >> 5, q = j & 31;
            int r = (chunk << 6) + row;
            float4 v = make_float4(0.f, 0.f, 0.f, 0.f);
            if (r < nNodes) {
                v = agg4[(size_t)r * 32 + q];
                float sc = rsI[r];
                v.x *= sc; v.y *= sc; v.z *= sc; v.w *= sc;
            }
            *(float4*)&Rb[buf][row][q * 4] = v;
        }
    };

    double lsum = 0.0;
    int cur = 0;
    int chunk = blockIdx.x;
    if (chunk < nChunks) stage(cur, chunk);
    __syncthreads();

    for (; chunk < nChunks; chunk += gridDim.x) {
        int nxt = chunk + gridDim.x;
        if (nxt < nChunks) stage(cur ^ 1, nxt);   // prefetch next chunk

        float accr[4][8];
        #pragma unroll
        for (int i = 0; i < 4; ++i)
            #pragma unroll
            for (int j = 0; j < 8; ++j) accr[i][j] = 0.f;

        #pragma unroll 2
        for (int k = 0; k < 128; k += 4) {
            const float4 a0 = *(const float4*)&Rb[cur][rg4 + 0][k];
            const float4 a1 = *(const float4*)&Rb[cur][rg4 + 1][k];
            const float4 a2 = *(const float4*)&Rb[cur][rg4 + 2][k];
            const float4 a3 = *(const float4*)&Rb[cur][rg4 + 3][k];
            KK_STEP(0, a0.x, a1.x, a2.x, a3.x)
            KK_STEP(1, a0.y, a1.y, a2.y, a3.y)
            KK_STEP(2, a0.z, a1.z, a2.z, a3.z)
            KK_STEP(3, a0.w, a1.w, a2.w, a3.w)
        }

        const int rbase = (chunk << 6) + rg4;
        #pragma unroll
        for (int i = 0; i < 4; ++i) {
            int r = rbase + i;
            if (r < nNodes) {
                float o0 = fmaxf(accr[i][0] + bA.x, 0.f);
                float o1 = fmaxf(accr[i][1] + bA.y, 0.f);
                float o2 = fmaxf(accr[i][2] + bA.z, 0.f);
                float o3 = fmaxf(accr[i][3] + bA.w, 0.f);
                float o4 = fmaxf(accr[i][4] + bB.x, 0.f);
                float o5 = fmaxf(accr[i][5] + bB.y, 0.f);
                float o6 = fmaxf(accr[i][6] + bB.z, 0.f);
                float o7 = fmaxf(accr[i][7] + bB.w, 0.f);
                if (FUSE) {
                    lsum += ((double)o0 + (double)o1) + ((double)o2 + (double)o3)
                          + ((double)o4 + (double)o5) + ((double)o6 + (double)o7);
                } else {
                    float sc = rsO[r];
                    float4 oA = make_float4(o0 * sc, o1 * sc, o2 * sc, o3 * sc);
                    float4 oB = make_float4(o4 * sc, o5 * sc, o6 * sc, o7 * sc);
                    *(float4*)&out[(size_t)r * 128 + c0] = oA;
                    *(float4*)&out[(size_t)r * 128 + c0 + 4] = oB;
                }
            }
        }
        __syncthreads();   // all reads of Rb[cur] done; next stage may overwrite
        cur ^= 1;
    }

    if (FUSE) {
        for (int off = 32; off; off >>= 1) lsum += __shfl_down(lsum, off, 64);
        __shared__ double wred[4];
        if ((t & 63) == 0) wred[t >> 6] = lsum;
        __syncthreads();
        if (t == 0) atomicAdd(acc, wred[0] + wred[1] + wred[2] + wred[3]);
    }
}

__global__ void finalize_kernel(const double* __restrict__ acc, float* __restrict__ out) {
    if (threadIdx.x == 0 && blockIdx.x == 0)
        out[0] = (float)(acc[0] / (4.0 * N_NODES * D));
}

extern "C" void kernel_launch(void* const* d_in, const int* in_sizes, int n_in,
                              void* d_out, int out_size, void* d_ws, size_t ws_size,
                              hipStream_t stream) {
    const float* x[4];
    const int* src[4];
    const int* dst[4];
    for (int g = 0; g < 4; ++g) {
        x[g]   = (const float*)d_in[3 * g + 0];
        src[g] = (const int*)  d_in[3 * g + 1];
        dst[g] = (const int*)  d_in[3 * g + 2];
    }
    const float* W1 = (const float*)d_in[12];
    const float* b1 = (const float*)d_in[13];
    const float* W2 = (const float*)d_in[14];
    const float* b2 = (const float*)d_in[15];
    float* out = (float*)d_out;

    // -------- workspace layout (4-byte units) --------
    // batched (ng=4) needs ~64.9 MB; fallback (ng=1) ~54.7 MB (proven in round 2)
    const size_t needBatched =
        (256 + 4 * (size_t)CPG + 12 * (size_t)N_NODES + 4 * (size_t)N_EDGES
         + 2 * (size_t)N_NODES * 32) * 16;  // float4 units *16B... computed below
    // compute exactly in bytes:
    const size_t unitsBatched = 256 + 4 * (size_t)CPG + 3 * 4 * (size_t)N_NODES
                              + 4 * (size_t)N_EDGES + 2 * (size_t)N_NODES * D;
    const int ng = (ws_size >= unitsBatched * 4 + 4096) ? 4 : 1;
    (void)needBatched;

    int* ws32 = (int*)d_ws;
    double* acc    = (double*)d_ws;                       // 8 B (slot 64 units)
    int* blockSums = ws32 + 64;                           // [4][32]
    int* cntBase   = ws32 + 256;                          // [ng][CPG]
    int* curBase   = cntBase + (size_t)ng * CPG;          // [ng][N]
    float* rsIBase = (float*)(curBase + (size_t)ng * N_NODES);
    float* rsOBase = rsIBase + (size_t)ng * N_NODES;
    int* eixBase   = (int*)(rsOBase + (size_t)ng * N_NODES);
    float* A       = (float*)(eixBase + (size_t)ng * N_EDGES);
    float* B       = A + (size_t)N_NODES * D;

    const int eGrid = (N_EDGES + 255) / 256;              // 2344
    const int gatherGrid = (N_NODES * 32) / 256;          // 6250
    const int gemmGrid = 256;

    hipMemsetAsync(acc, 0, sizeof(double), stream);

    if (ng == 4) {
        hipMemsetAsync(cntBase, 0, 4 * (size_t)CPG * sizeof(int), stream);
        hist_kernel<<<dim3(eGrid, 4), 256, 0, stream>>>(
            src[0], src[1], src[2], src[3], dst[0], dst[1], dst[2], dst[3],
            cntBase, 0, N_EDGES);
        scanA_kernel<<<dim3(SCAN_NBLOCKS, 4), SCAN_BLOCK, 0, stream>>>(cntBase, blockSums);
        scanC_kernel<<<dim3(SCAN_NBLOCKS, 4), SCAN_BLOCK, 0, stream>>>(
            cntBase, blockSums, curBase, rsIBase, rsOBase);
        scatter_kernel<<<dim3(eGrid, 4), 256, 0, stream>>>(
            src[0], src[1], src[2], src[3], dst[0], dst[1], dst[2], dst[3],
            curBase, eixBase, 0, N_EDGES);

        for (int g = 0; g < 4; ++g) {
            const int* rowptr = cntBase + (size_t)g * CPG;
            const int* eidx   = eixBase + (size_t)g * N_EDGES;
            const float* rsI  = rsIBase + (size_t)g * N_NODES;
            const float* rsO  = rsOBase + (size_t)g * N_NODES;
            gather_kernel<1><<<gatherGrid, 256, 0, stream>>>(
                rowptr, eidx, (const float4*)x[g], rsO, (float4*)B, N_NODES);
            gemm_kernel<0><<<gemmGrid, 256, 0, stream>>>(B, rsI, rsO, W1, b1, A, nullptr, N_NODES);
            gather_kernel<0><<<gatherGrid, 256, 0, stream>>>(
                rowptr, eidx, (const float4*)A, nullptr, (float4*)B, N_NODES);
            gemm_kernel<1><<<gemmGrid, 256, 0, stream>>>(B, rsI, nullptr, W2, b2, nullptr, acc, N_NODES);
        }
    } else {
        for (int g = 0; g < 4; ++g) {
            hipMemsetAsync(cntBase, 0, (size_t)CPG * sizeof(int), stream);
            hist_kernel<<<dim3(eGrid, 1), 256, 0, stream>>>(
                src[0], src[1], src[2], src[3], dst[0], dst[1], dst[2], dst[3],
                cntBase, g, N_EDGES);
            scanA_kernel<<<dim3(SCAN_NBLOCKS, 1), SCAN_BLOCK, 0, stream>>>(cntBase, blockSums);
            scanC_kernel<<<dim3(SCAN_NBLOCKS, 1), SCAN_BLOCK, 0, stream>>>(
                cntBase, blockSums, curBase, rsIBase, rsOBase);
            scatter_kernel<<<dim3(eGrid, 1), 256, 0, stream>>>(
                src[0], src[1], src[2], src[3], dst[0], dst[1], dst[2], dst[3],
                curBase, eixBase, g, N_EDGES);

            gather_kernel<1><<<gatherGrid, 256, 0, stream>>>(
                cntBase, eixBase, (const float4*)x[g], rsOBase, (float4*)B, N_NODES);
            gemm_kernel<0><<<gemmGrid, 256, 0, stream>>>(B, rsIBase, rsOBase, W1, b1, A, nullptr, N_NODES);
            gather_kernel<0><<<gatherGrid, 256, 0, stream>>>(
                cntBase, eixBase, (const float4*)A, nullptr, (float4*)B, N_NODES);
            gemm_kernel<1><<<gemmGrid, 256, 0, stream>>>(B, rsIBase, nullptr, W2, b2, nullptr, acc, N_NODES);
        }
    }

    finalize_kernel<<<1, 64, 0, stream>>>(acc, out);
}

// Round 4
// 901.299 us; speedup vs baseline: 10.4147x; 1.2041x over previous
//
#include <hip/hip_runtime.h>
#include <hip/hip_bf16.h>

#define N_NODES 50000
#define N_EDGES 600000
#define D 128

#define SCAN_BLOCK 256
#define SCAN_ELEMS 8
#define SCAN_PER_BLOCK (SCAN_BLOCK * SCAN_ELEMS)          // 2048
#define SCAN_NBLOCKS ((N_NODES + SCAN_PER_BLOCK - 1) / SCAN_PER_BLOCK)  // 25

#define CPG 100032   // per-graph counter region: cntI(N+1) + cntO(N), padded (ints)
#define NBUCK 64
#define BUCK_R 782   // ceil(N_NODES/NBUCK); 64*782 = 50048 >= N
#define EPB 2048     // edges per phaseA block

__device__ __forceinline__ const int* pick4(const int* a, const int* b,
                                            const int* c, const int* d, int g) {
    return g == 0 ? a : g == 1 ? b : g == 2 ? c : d;
}

__device__ __forceinline__ float bf2f(unsigned short u) {
    return __uint_as_float((unsigned)u << 16);
}
__device__ __forceinline__ unsigned bfpair(float a, float b) {   // RNE pack: lo=a, hi=b
    unsigned ua = __float_as_uint(a); ua = (ua + 0x7FFF + ((ua >> 16) & 1)) >> 16;
    unsigned ub = __float_as_uint(b); ub = (ub + 0x7FFF + ((ub >> 16) & 1)) >> 16;
    return ua | (ub << 16);
}

// --- histogram: cntI[dst]++, cntO[src]++
__global__ void hist_kernel(const int* s0, const int* s1, const int* s2, const int* s3,
                            const int* d0, const int* d1, const int* d2, const int* d3,
                            int* __restrict__ cntBase, int gFirst, int nEdges) {
    int gi = blockIdx.y;
    const int* src = pick4(s0, s1, s2, s3, gFirst + gi);
    const int* dst = pick4(d0, d1, d2, d3, gFirst + gi);
    int* cntI = cntBase + (size_t)gi * CPG;
    int* cntO = cntI + (N_NODES + 1);
    int e = blockIdx.x * blockDim.x + threadIdx.x;
    if (e < nEdges) {
        atomicAdd(&cntI[dst[e]], 1);
        atomicAdd(&cntO[src[e]], 1);
    }
}

// --- scan phase A: per-block sums of cntI
__global__ __launch_bounds__(SCAN_BLOCK) void scanA_kernel(
        const int* __restrict__ cntBase, int* __restrict__ blockSums) {
    int gi = blockIdx.y;
    const int* cntI = cntBase + (size_t)gi * CPG;
    int t = threadIdx.x, bk = blockIdx.x;
    int base = bk * SCAN_PER_BLOCK + t * SCAN_ELEMS;
    int s = 0;
    #pragma unroll
    for (int j = 0; j < SCAN_ELEMS; ++j) {
        int i = base + j;
        if (i < N_NODES) s += cntI[i];
    }
    for (int off = 32; off; off >>= 1) s += __shfl_down(s, off, 64);
    __shared__ int wsum[SCAN_BLOCK / 64];
    if ((t & 63) == 0) wsum[t >> 6] = s;
    __syncthreads();
    if (t == 0) {
        int r = 0;
        #pragma unroll
        for (int w = 0; w < SCAN_BLOCK / 64; ++w) r += wsum[w];
        blockSums[gi * 32 + bk] = r;
    }
}

// --- scan phase C: rowptr (in place over cntI), cursor copy, rsqrt norms
__global__ __launch_bounds__(SCAN_BLOCK) void scanC_kernel(
        int* __restrict__ cntBase, const int* __restrict__ blockSums,
        int* __restrict__ curBase, float* __restrict__ rsIBase,
        float* __restrict__ rsOBase) {
    int gi = blockIdx.y;
    int* cntI = cntBase + (size_t)gi * CPG;
    const int* cntO = cntI + (N_NODES + 1);
    int* rowptr = cntI;
    int* cursor = curBase + (size_t)gi * N_NODES;
    float* rsI = rsIBase + (size_t)gi * N_NODES;
    float* rsO = rsOBase + (size_t)gi * N_NODES;

    int t = threadIdx.x, bk = blockIdx.x;

    __shared__ int boffs[SCAN_NBLOCKS];
    if (t == 0) {
        int r = 0;
        for (int i = 0; i < SCAN_NBLOCKS; ++i) { boffs[i] = r; r += blockSums[gi * 32 + i]; }
    }

    int base = bk * SCAN_PER_BLOCK + t * SCAN_ELEMS;
    int local[SCAN_ELEMS];
    int s = 0;
    #pragma unroll
    for (int j = 0; j < SCAN_ELEMS; ++j) {
        int i = base + j;
        local[j] = (i < N_NODES) ? cntI[i] : 0;
        s += local[j];
    }
    int lane = t & 63, w = t >> 6;
    int v = s;
    for (int off = 1; off < 64; off <<= 1) {
        int u = __shfl_up(v, off, 64);
        if (lane >= off) v += u;
    }
    __shared__ int wsum[SCAN_BLOCK / 64];
    if (lane == 63) wsum[w] = v;
    __syncthreads();
    if (t == 0) {
        int r = 0;
        #pragma unroll
        for (int i = 0; i < SCAN_BLOCK / 64; ++i) { int x = wsum[i]; wsum[i] = r; r += x; }
    }
    __syncthreads();
    int running = boffs[bk] + wsum[w] + (v - s);
    #pragma unroll
    for (int j = 0; j < SCAN_ELEMS; ++j) {
        int i = base + j;
        if (i < N_NODES) {
            rowptr[i] = running;
            cursor[i] = running;
            running += local[j];
            rsI[i] = 1.0f / sqrtf(fmaxf((float)local[j], 1.0f));
            rsO[i] = 1.0f / sqrtf(fmaxf((float)cntO[i], 1.0f));
        }
    }
    if (bk == SCAN_NBLOCKS - 1 && t == SCAN_BLOCK - 1)
        rowptr[N_NODES] = N_EDGES;
}

// --- phase A: bucket-scatter (dst,src) pairs into coarse-bucket regions.
// Bucket b's region in `pairs` = [rowptr[b*BUCK_R], rowptr[min((b+1)*BUCK_R,N)]).
__global__ __launch_bounds__(256) void phaseA_kernel(
        const int* s0, const int* s1, const int* s2, const int* s3,
        const int* d0, const int* d1, const int* d2, const int* d3,
        const int* __restrict__ cntBase, int* __restrict__ bucketCur,
        int2* __restrict__ pairsBase, int gFirst, int nEdges) {
    int gi = blockIdx.y;
    const int* src = pick4(s0, s1, s2, s3, gFirst + gi);
    const int* dst = pick4(d0, d1, d2, d3, gFirst + gi);
    const int* rowptr = cntBase + (size_t)gi * CPG;
    int* bCur = bucketCur + gi * NBUCK;
    int2* pr = pairsBase + (size_t)gi * N_EDGES;

    __shared__ int cnt[NBUCK];
    __shared__ int gpos[NBUCK];
    __shared__ int lcur[NBUCK];
    int t = threadIdx.x;
    if (t < NBUCK) cnt[t] = 0;
    __syncthreads();

    int base = blockIdx.x * EPB + t;
    int myDst[8], mySrc[8], myBin[8];
    #pragma unroll
    for (int j = 0; j < 8; ++j) {
        int e = base + j * 256;
        if (e < nEdges) {
            myDst[j] = dst[e];
            mySrc[j] = src[e];
            myBin[j] = myDst[j] / BUCK_R;
            atomicAdd(&cnt[myBin[j]], 1);
        } else {
            myBin[j] = -1;
        }
    }
    __syncthreads();
    if (t < NBUCK) {
        int c = cnt[t];
        int p = (c > 0) ? atomicAdd(&bCur[t], c) : 0;
        gpos[t] = rowptr[t * BUCK_R] + p;
        lcur[t] = 0;
    }
    __syncthreads();
    #pragma unroll
    for (int j = 0; j < 8; ++j) {
        if (myBin[j] >= 0) {
            int loc = atomicAdd(&lcur[myBin[j]], 1);
            pr[gpos[myBin[j]] + loc] = make_int2(myDst[j], mySrc[j]);
        }
    }
}

// --- phase B: fine scatter within bucket (cursor/eidx lines are block-local in L2)
__global__ __launch_bounds__(256) void phaseB_kernel(
        const int* __restrict__ cntBase, const int2* __restrict__ pairsBase,
        int* __restrict__ curBase, int* __restrict__ eixBase) {
    int gi = blockIdx.y;
    const int* rowptr = cntBase + (size_t)gi * CPG;
    const int2* pr = pairsBase + (size_t)gi * N_EDGES;
    int* cursor = curBase + (size_t)gi * N_NODES;
    int* eidx = eixBase + (size_t)gi * N_EDGES;
    int bk = blockIdx.x;
    int lo = bk * BUCK_R;
    int hi = (bk + 1) * BUCK_R; if (hi > N_NODES) hi = N_NODES;
    int beg = rowptr[lo], end = rowptr[hi];
    for (int p = beg + threadIdx.x; p < end; p += 256) {
        int2 e = pr[p];
        int pos = atomicAdd(&cursor[e.x], 1);
        eidx[pos] = e.y;
    }
}

// --- x -> bf16 conversion with rsO pre-scale: xb[i] (8 bf16 per uint4)
__global__ void xconv_kernel(const float4* __restrict__ x, const float* __restrict__ rsO,
                             uint4* __restrict__ xb, int n /* N*16 */) {
    int i = blockIdx.x * blockDim.x + threadIdx.x;
    if (i >= n) return;
    float sc = rsO[i >> 4];
    float4 a = x[i * 2];
    float4 b = x[i * 2 + 1];
    uint4 o;
    o.x = bfpair(a.x * sc, a.y * sc);
    o.y = bfpair(a.z * sc, a.w * sc);
    o.z = bfpair(b.x * sc, b.y * sc);
    o.w = bfpair(b.z * sc, b.w * sc);
    xb[i] = o;
}

// --- gather SpMM (bf16 source rows): out[r][:] = sum_{p in row r} h[eidx[p]][:]
__global__ __launch_bounds__(256) void gather_kernel(
        const int* __restrict__ rowptr, const int* __restrict__ eidx,
        const ushort4* __restrict__ h,   // 32 ushort4 (=128 bf16) per row
        float4* __restrict__ out, int nNodes) {
    int gid = blockIdx.x * blockDim.x + threadIdx.x;
    int r = gid >> 5;
    int q = gid & 31;
    if (r >= nNodes) return;
    int p = rowptr[r], end = rowptr[r + 1];
    float4 accA = make_float4(0.f, 0.f, 0.f, 0.f);
    float4 accB = make_float4(0.f, 0.f, 0.f, 0.f);
    for (; p + 2 <= end; p += 2) {
        ushort4 u0 = h[(size_t)eidx[p] * 32 + q];
        ushort4 u1 = h[(size_t)eidx[p + 1] * 32 + q];
        accA.x += bf2f(u0.x); accA.y += bf2f(u0.y);
        accA.z += bf2f(u0.z); accA.w += bf2f(u0.w);
        accB.x += bf2f(u1.x); accB.y += bf2f(u1.y);
        accB.z += bf2f(u1.z); accB.w += bf2f(u1.w);
    }
    if (p < end) {
        ushort4 u0 = h[(size_t)eidx[p] * 32 + q];
        accA.x += bf2f(u0.x); accA.y += bf2f(u0.y);
        accA.z += bf2f(u0.z); accA.w += bf2f(u0.w);
    }
    accA.x += accB.x; accA.y += accB.y; accA.z += accB.z; accA.w += accB.w;
    out[(size_t)r * 32 + q] = accA;
}

// --- persistent GEMM: W staged once/block, double-buffered 64-row chunks,
//     thread tile 4 rows x 8 cols. o = relu(rsI[r]*(agg[r]@W) + b)
//     FUSE==0: outb[r][c] = bf16(o * rsO[r]);  FUSE==1: acc += sum(o)
#define ROW_FMA(i, av)                                         \
    accr[i][0] = fmaf(av, wA.x, accr[i][0]);                   \
    accr[i][1] = fmaf(av, wA.y, accr[i][1]);                   \
    accr[i][2] = fmaf(av, wA.z, accr[i][2]);                   \
    accr[i][3] = fmaf(av, wA.w, accr[i][3]);                   \
    accr[i][4] = fmaf(av, wB.x, accr[i][4]);                   \
    accr[i][5] = fmaf(av, wB.y, accr[i][5]);                   \
    accr[i][6] = fmaf(av, wB.z, accr[i][6]);                   \
    accr[i][7] = fmaf(av, wB.w, accr[i][7]);

#define KK_STEP(kk, v0, v1, v2, v3)                            \
    {                                                          \
        const float4 wA = *(const float4*)&Wl[k + kk][c0];     \
        const float4 wB = *(const float4*)&Wl[k + kk][c0 + 4]; \
        ROW_FMA(0, v0) ROW_FMA(1, v1)                          \
        ROW_FMA(2, v2) ROW_FMA(3, v3)                          \
    }

template <int FUSE>
__global__ __launch_bounds__(256) void gemm_kernel(
        const float* __restrict__ agg, const float* __restrict__ rsI,
        const float* __restrict__ rsO,
        const float* __restrict__ W, const float* __restrict__ b,
        unsigned short* __restrict__ outb, double* __restrict__ acc, int nNodes) {
    __shared__ float Wl[128][128];       // 64 KiB, [k][c]
    __shared__ float Rb[2][64][136];     // 68 KiB
    const int t = threadIdx.x;

    {   // stage W once
        const float4* W4 = (const float4*)W;
        float4* Wl4 = (float4*)&Wl[0][0];
        #pragma unroll
        for (int it = 0; it < 16; ++it)
            Wl4[t + it * 256] = W4[t + it * 256];
    }

    const int cg = t & 15;
    const int rg4 = (t >> 4) * 4;
    const int c0 = cg * 8;
    const int nChunks = (nNodes + 63) >> 6;

    const float4* b4 = (const float4*)b;
    const float4 bA = b4[cg * 2];
    const float4 bB = b4[cg * 2 + 1];

    auto stage = [&](int buf, int chunk) {
        const float4* agg4 = (const float4*)agg;
        #pragma unroll
        for (int it = 0; it < 8; ++it) {
            int j = t + it * 256;
            int row = j >> 5, q = j & 31;
            int r = (chunk << 6) + row;
            float4 v = make_float4(0.f, 0.f, 0.f, 0.f);
            if (r < nNodes) {
                v = agg4[(size_t)r * 32 + q];
                float sc = rsI[r];
                v.x *= sc; v.y *= sc; v.z *= sc; v.w *= sc;
            }
            *(float4*)&Rb[buf][row][q * 4] = v;
        }
    };

    double lsum = 0.0;
    int cur = 0;
    int chunk = blockIdx.x;
    if (chunk < nChunks) stage(cur, chunk);
    __syncthreads();

    for (; chunk < nChunks; chunk += gridDim.x) {
        int nxt = chunk + gridDim.x;
        if (nxt < nChunks) stage(cur ^ 1, nxt);

        float accr[4][8];
        #pragma unroll
        for (int i = 0; i < 4; ++i)
            #pragma unroll
            for (int j = 0; j < 8; ++j) accr[i][j] = 0.f;

        #pragma unroll 2
        for (int k = 0; k < 128; k += 4) {
            const float4 a0 = *(const float4*)&Rb[cur][rg4 + 0][k];
            const float4 a1 = *(const float4*)&Rb[cur][rg4 + 1][k];
            const float4 a2 = *(const float4*)&Rb[cur][rg4 + 2][k];
            const float4 a3 = *(const float4*)&Rb[cur][rg4 + 3][k];
            KK_STEP(0, a0.x, a1.x, a2.x, a3.x)
            KK_STEP(1, a0.y, a1.y, a2.y, a3.y)
            KK_STEP(2, a0.z, a1.z, a2.z, a3.z)
            KK_STEP(3, a0.w, a1.w, a2.w, a3.w)
        }

        const int rbase = (chunk << 6) + rg4;
        #pragma unroll
        for (int i = 0; i < 4; ++i) {
            int r = rbase + i;
            if (r < nNodes) {
                float o0 = fmaxf(accr[i][0] + bA.x, 0.f);
                float o1 = fmaxf(accr[i][1] + bA.y, 0.f);
                float o2 = fmaxf(accr[i][2] + bA.z, 0.f);
                float o3 = fmaxf(accr[i][3] + bA.w, 0.f);
                float o4 = fmaxf(accr[i][4] + bB.x, 0.f);
                float o5 = fmaxf(accr[i][5] + bB.y, 0.f);
                float o6 = fmaxf(accr[i][6] + bB.z, 0.f);
                float o7 = fmaxf(accr[i][7] + bB.w, 0.f);
                if (FUSE) {
                    lsum += ((double)o0 + (double)o1) + ((double)o2 + (double)o3)
                          + ((double)o4 + (double)o5) + ((double)o6 + (double)o7);
                } else {
                    float sc = rsO[r];
                    uint4 ov;
                    ov.x = bfpair(o0 * sc, o1 * sc);
                    ov.y = bfpair(o2 * sc, o3 * sc);
                    ov.z = bfpair(o4 * sc, o5 * sc);
                    ov.w = bfpair(o6 * sc, o7 * sc);
                    *(uint4*)&outb[(size_t)r * 128 + c0] = ov;
                }
            }
        }
        __syncthreads();
        cur ^= 1;
    }

    if (FUSE) {
        for (int off = 32; off; off >>= 1) lsum += __shfl_down(lsum, off, 64);
        __shared__ double wred[4];
        if ((t & 63) == 0) wred[t >> 6] = lsum;
        __syncthreads();
        if (t == 0) atomicAdd(acc, wred[0] + wred[1] + wred[2] + wred[3]);
    }
}

__global__ void finalize_kernel(const double* __restrict__ acc, float* __restrict__ out) {
    if (threadIdx.x == 0 && blockIdx.x == 0)
        out[0] = (float)(acc[0] / (4.0 * N_NODES * D));
}

extern "C" void kernel_launch(void* const* d_in, const int* in_sizes, int n_in,
                              void* d_out, int out_size, void* d_ws, size_t ws_size,
                              hipStream_t stream) {
    const float* x[4];
    const int* src[4];
    const int* dst[4];
    for (int g = 0; g < 4; ++g) {
        x[g]   = (const float*)d_in[3 * g + 0];
        src[g] = (const int*)  d_in[3 * g + 1];
        dst[g] = (const int*)  d_in[3 * g + 2];
    }
    const float* W1 = (const float*)d_in[12];
    const float* b1 = (const float*)d_in[13];
    const float* W2 = (const float*)d_in[14];
    const float* b2 = (const float*)d_in[15];
    float* out = (float*)d_out;

    // -------- workspace layout (4-byte units) --------
    // header: acc(64) + blockSums(128) + bucketCur(256) = 448 units
    auto unitsFor = [](int ng) -> size_t {
        return 448 + (size_t)ng * CPG + 3 * (size_t)ng * N_NODES
             + (size_t)ng * N_EDGES + (size_t)N_NODES * 64   // xbA (bf16 N*128)
             + (size_t)N_NODES * 128;                        // B (fp32); pairs overlay B
    };
    const int ng = (ws_size >= unitsFor(4) * 4 + 4096) ? 4 : 1;

    int* ws32 = (int*)d_ws;
    double* acc     = (double*)d_ws;
    int* blockSums  = ws32 + 64;
    int* bucketCur  = ws32 + 192;
    int* cntBase    = ws32 + 448;
    int* curBase    = cntBase + (size_t)ng * CPG;
    float* rsIBase  = (float*)(curBase + (size_t)ng * N_NODES);
    float* rsOBase  = rsIBase + (size_t)ng * N_NODES;
    int* eixBase    = (int*)(rsOBase + (size_t)ng * N_NODES);
    unsigned short* xbA = (unsigned short*)(eixBase + (size_t)ng * N_EDGES);
    float* B        = (float*)(xbA + (size_t)N_NODES * D);
    int2* pairsBase = (int2*)B;   // overlay: pairs dead before B is first written

    const int eGrid  = (N_EDGES + 255) / 256;
    const int paGrid = (N_EDGES + EPB - 1) / EPB;          // 293
    const int gatherGrid = (N_NODES * 32) / 256;           // 6250
    const int xconvGrid  = (N_NODES * 16 + 255) / 256;     // 3125
    const int gemmGrid = 256;

    if (ng == 4) {
        // one memset covers acc + blockSums + bucketCur + all cntI/cntO
        hipMemsetAsync(d_ws, 0, (448 + 4 * (size_t)CPG) * sizeof(int), stream);
        hist_kernel<<<dim3(eGrid, 4), 256, 0, stream>>>(
            src[0], src[1], src[2], src[3], dst[0], dst[1], dst[2], dst[3],
            cntBase, 0, N_EDGES);
        scanA_kernel<<<dim3(SCAN_NBLOCKS, 4), SCAN_BLOCK, 0, stream>>>(cntBase, blockSums);
        scanC_kernel<<<dim3(SCAN_NBLOCKS, 4), SCAN_BLOCK, 0, stream>>>(
            cntBase, blockSums, curBase, rsIBase, rsOBase);
        phaseA_kernel<<<dim3(paGrid, 4), 256, 0, stream>>>(
            src[0], src[1], src[2], src[3], dst[0], dst[1], dst[2], dst[3],
            cntBase, bucketCur, pairsBase, 0, N_EDGES);
        phaseB_kernel<<<dim3(NBUCK, 4), 256, 0, stream>>>(
            cntBase, pairsBase, curBase, eixBase);

        for (int g = 0; g < 4; ++g) {
            const int* rowptr = cntBase + (size_t)g * CPG;
            const int* eidx   = eixBase + (size_t)g * N_EDGES;
            const float* rsI  = rsIBase + (size_t)g * N_NODES;
            const float* rsO  = rsOBase + (size_t)g * N_NODES;
            xconv_kernel<<<xconvGrid, 256, 0, stream>>>(
                (const float4*)x[g], rsO, (uint4*)xbA, N_NODES * 16);
            gather_kernel<<<gatherGrid, 256, 0, stream>>>(
                rowptr, eidx, (const ushort4*)xbA, (float4*)B, N_NODES);
            gemm_kernel<0><<<gemmGrid, 256, 0, stream>>>(B, rsI, rsO, W1, b1, xbA, nullptr, N_NODES);
            gather_kernel<<<gatherGrid, 256, 0, stream>>>(
                rowptr, eidx, (const ushort4*)xbA, (float4*)B, N_NODES);
            gemm_kernel<1><<<gemmGrid, 256, 0, stream>>>(B, rsI, nullptr, W2, b2, nullptr, acc, N_NODES);
        }
    } else {
        hipMemsetAsync(d_ws, 0, 448 * sizeof(int), stream);
        for (int g = 0; g < 4; ++g) {
            hipMemsetAsync(cntBase, 0, (size_t)CPG * sizeof(int), stream);
            hipMemsetAsync(bucketCur, 0, NBUCK * sizeof(int), stream);
            hist_kernel<<<dim3(eGrid, 1), 256, 0, stream>>>(
                src[0], src[1], src[2], src[3], dst[0], dst[1], dst[2], dst[3],
                cntBase, g, N_EDGES);
            scanA_kernel<<<dim3(SCAN_NBLOCKS, 1), SCAN_BLOCK, 0, stream>>>(cntBase, blockSums);
            scanC_kernel<<<dim3(SCAN_NBLOCKS, 1), SCAN_BLOCK, 0, stream>>>(
                cntBase, blockSums, curBase, rsIBase, rsOBase);
            phaseA_kernel<<<dim3(paGrid, 1), 256, 0, stream>>>(
                src[0], src[1], src[2], src[3], dst[0], dst[1], dst[2], dst[3],
                cntBase, bucketCur, pairsBase, g, N_EDGES);
            phaseB_kernel<<<dim3(NBUCK, 1), 256, 0, stream>>>(
                cntBase, pairsBase, curBase, eixBase);

            xconv_kernel<<<xconvGrid, 256, 0, stream>>>(
                (const float4*)x[g], rsOBase, (uint4*)xbA, N_NODES * 16);
            gather_kernel<<<gatherGrid, 256, 0, stream>>>(
                cntBase, eixBase, (const ushort4*)xbA, (float4*)B, N_NODES);
            gemm_kernel<0><<<gemmGrid, 256, 0, stream>>>(B, rsIBase, rsOBase, W1, b1, xbA, nullptr, N_NODES);
            gather_kernel<<<gatherGrid, 256, 0, stream>>>(
                cntBase, eixBase, (const ushort4*)xbA, (float4*)B, N_NODES);
            gemm_kernel<1><<<gemmGrid, 256, 0, stream>>>(B, rsIBase, nullptr, W2, b2, nullptr, acc, N_NODES);
        }
    }

    finalize_kernel<<<1, 64, 0, stream>>>(acc, out);
}

// Round 5
// 473.081 us; speedup vs baseline: 19.8417x; 1.9052x over previous
//
#include <hip/hip_runtime.h>
#include <hip/hip_bf16.h>

#define N_NODES 50000
#define N_EDGES 600000
#define D 128

#define NBUCK 64
#define BUCK_R 782      // ceil(N/64); 64*782 = 50048
#define BCAP 16384      // per-bucket capacity (mean 9375, std 96 -> 73 sigma headroom)
#define EPB 2048        // edges per phaseA block

typedef __attribute__((ext_vector_type(8))) short bf16x8;
typedef __attribute__((ext_vector_type(4))) float f32x4;

__device__ __forceinline__ const int* pick4(const int* a, const int* b,
                                            const int* c, const int* d, int g) {
    return g == 0 ? a : g == 1 ? b : g == 2 ? c : d;
}

__device__ __forceinline__ float bf2f(unsigned short u) {
    return __uint_as_float((unsigned)u << 16);
}
__device__ __forceinline__ unsigned bfpair(float a, float b) {   // RNE pack: lo=a, hi=b
    unsigned ua = __float_as_uint(a); ua = (ua + 0x7FFF + ((ua >> 16) & 1)) >> 16;
    unsigned ub = __float_as_uint(b); ub = (ub + 0x7FFF + ((ub >> 16) & 1)) >> 16;
    return ua | (ub << 16);
}
__device__ __forceinline__ unsigned short f2bf(float x) {
    unsigned u = __float_as_uint(x); u = (u + 0x7FFF + ((u >> 16) & 1)) >> 16;
    return (unsigned short)u;
}

// ---------- phase A: bucket edges by dst (pairs) and by src (svals) ----------
// pairs entry: (dstLocal<<16)|src  (dstLocal<782<1024, src<50000<65536)
__global__ __launch_bounds__(256) void phaseA_kernel(
        const int* s0, const int* s1, const int* s2, const int* s3,
        const int* d0, const int* d1, const int* d2, const int* d3,
        int* __restrict__ bCurD, int* __restrict__ bCurS,
        int* __restrict__ pairs, unsigned short* __restrict__ svals, int nEdges) {
    int gi = blockIdx.y;
    const int* src = pick4(s0, s1, s2, s3, gi);
    const int* dst = pick4(d0, d1, d2, d3, gi);
    int* pg = pairs + (size_t)gi * NBUCK * BCAP;
    unsigned short* sg = svals + (size_t)gi * NBUCK * BCAP;

    __shared__ int cntD[64], cntS[64], gposD[64], gposS[64], lcurD[64], lcurS[64];
    int t = threadIdx.x;
    if (t < 64) { cntD[t] = 0; cntS[t] = 0; }
    __syncthreads();

    int myD[8], myS[8];
    int base = blockIdx.x * EPB + t;
    #pragma unroll
    for (int j = 0; j < 8; ++j) {
        int e = base + j * 256;
        if (e < nEdges) {
            myD[j] = dst[e]; myS[j] = src[e];
            atomicAdd(&cntD[myD[j] / BUCK_R], 1);
            atomicAdd(&cntS[myS[j] / BUCK_R], 1);
        } else myD[j] = -1;
    }
    __syncthreads();
    if (t < 64) {
        int c = cntD[t];
        gposD[t] = t * BCAP + (c ? atomicAdd(&bCurD[gi * 64 + t], c) : 0);
        lcurD[t] = 0;
        c = cntS[t];
        gposS[t] = t * BCAP + (c ? atomicAdd(&bCurS[gi * 64 + t], c) : 0);
        lcurS[t] = 0;
    }
    __syncthreads();
    #pragma unroll
    for (int j = 0; j < 8; ++j) {
        if (myD[j] >= 0) {
            int bD = myD[j] / BUCK_R, bS = myS[j] / BUCK_R;
            int lp = atomicAdd(&lcurD[bD], 1);
            pg[gposD[bD] + lp] = ((myD[j] - bD * BUCK_R) << 16) | myS[j];
            int ls = atomicAdd(&lcurS[bS], 1);
            sg[gposS[bS] + ls] = (unsigned short)(myS[j] - bS * BUCK_R);
        }
    }
}

// ---------- csrB: per (graph,bucket): LDS hist + scan + scatter -> rowptr/rsI/eidx ----------
__global__ __launch_bounds__(256) void csrB_kernel(
        const int* __restrict__ bCurD, const int* __restrict__ pairs,
        int* __restrict__ rowptrBase, int* __restrict__ eixBase,
        float* __restrict__ rsIBase) {
    int gi = blockIdx.y, b = blockIdx.x;
    int* rowptr = rowptrBase + (size_t)gi * (N_NODES + 1);
    int* eidx = eixBase + (size_t)gi * N_EDGES;
    float* rsI = rsIBase + (size_t)gi * N_NODES;
    const int* pg = pairs + ((size_t)gi * NBUCK + b) * BCAP;
    const int* bCur = bCurD + gi * 64;

    __shared__ int P[BCAP];        // 64 KiB
    __shared__ int cnt[1024];
    __shared__ int cur[1024];
    __shared__ int wpart[4];
    __shared__ int sbase;

    int t = threadIdx.x;
    int nb = bCur[b]; if (nb > BCAP) nb = BCAP;

    if (t < 64) {   // base = sum of previous bucket counts (wave 0)
        int v = (t < b) ? min(bCur[t], BCAP) : 0;
        for (int off = 32; off; off >>= 1) v += __shfl_down(v, off, 64);
        if (t == 0) sbase = v;
    }
    for (int i = t; i < 1024; i += 256) cnt[i] = 0;
    __syncthreads();                              // S1
    int base = sbase;

    for (int i = t; i < nb; i += 256) {
        int p = pg[i];
        P[i] = p;
        atomicAdd(&cnt[p >> 16], 1);
    }
    __syncthreads();                              // S2

    // scan 1024 bins, 4 per thread
    int c0 = cnt[t * 4 + 0], c1 = cnt[t * 4 + 1], c2 = cnt[t * 4 + 2], c3 = cnt[t * 4 + 3];
    int ts = c0 + c1 + c2 + c3;
    int lane = t & 63, w = t >> 6;
    int incl = ts;
    for (int off = 1; off < 64; off <<= 1) {
        int u = __shfl_up(incl, off, 64);
        if (lane >= off) incl += u;
    }
    if (lane == 63) wpart[w] = incl;
    __syncthreads();                              // S3
    int wb = 0;
    #pragma unroll
    for (int i = 0; i < 4; ++i) if (i < w) wb += wpart[i];
    int ex = wb + incl - ts;
    cur[t * 4 + 0] = ex;
    cur[t * 4 + 1] = ex + c0;
    cur[t * 4 + 2] = ex + c0 + c1;
    cur[t * 4 + 3] = ex + c0 + c1 + c2;
    __syncthreads();                              // S4

    int lo = b * BUCK_R;
    int nh = N_NODES - lo; if (nh > BUCK_R) nh = BUCK_R;
    for (int i = t; i < nh; i += 256) {
        rowptr[lo + i] = base + cur[i];
        rsI[lo + i] = 1.0f / sqrtf(fmaxf((float)cnt[i], 1.0f));
    }
    if (b == NBUCK - 1 && t == 0) rowptr[N_NODES] = N_EDGES;
    __syncthreads();                              // S5

    for (int i = t; i < nb; i += 256) {
        int p = P[i];
        int pos = atomicAdd(&cur[p >> 16], 1);
        eidx[base + pos] = p & 0xFFFF ? (p & 0xFFFF) : (p & 0xFFFF);  // src
    }
}

// ---------- csrC: per (graph,bucket): LDS hist of src -> rsO ----------
__global__ __launch_bounds__(256) void csrC_kernel(
        const int* __restrict__ bCurS, const unsigned short* __restrict__ svals,
        float* __restrict__ rsOBase) {
    int gi = blockIdx.y, b = blockIdx.x;
    float* rsO = rsOBase + (size_t)gi * N_NODES;
    const unsigned short* sg = svals + ((size_t)gi * NBUCK + b) * BCAP;
    __shared__ int cnt[1024];
    int t = threadIdx.x;
    for (int i = t; i < 1024; i += 256) cnt[i] = 0;
    __syncthreads();
    int ns = bCurS[gi * 64 + b]; if (ns > BCAP) ns = BCAP;
    for (int i = t; i < ns; i += 256) atomicAdd(&cnt[sg[i]], 1);
    __syncthreads();
    int lo = b * BUCK_R;
    int nh = N_NODES - lo; if (nh > BUCK_R) nh = BUCK_R;
    for (int i = t; i < nh; i += 256)
        rsO[lo + i] = 1.0f / sqrtf(fmaxf((float)cnt[i], 1.0f));
}

// ---------- W fp32 -> packed bf16 MFMA B-fragment layout ----------
// Wp[((kc*8+nt)*64+lane)*4 + j2] = pack(W[k][col], W[k+1][col]),
// k = kc*32 + (lane>>4)*8 + 2*j2, col = nt*16 + (lane&15)
__global__ void wconv_kernel(const float* __restrict__ W1, const float* __restrict__ W2,
                             unsigned* __restrict__ Wp1, unsigned* __restrict__ Wp2) {
    const float* W = blockIdx.y ? W2 : W1;
    unsigned* Wp = blockIdx.y ? Wp2 : Wp1;
    int o = blockIdx.x * 256 + threadIdx.x;      // 0..8191
    int j2 = o & 3, lane = (o >> 2) & 63, nt = (o >> 8) & 7, kc = o >> 11;
    int k = kc * 32 + (lane >> 4) * 8 + j2 * 2;
    int col = nt * 16 + (lane & 15);
    Wp[o] = bfpair(W[k * 128 + col], W[(k + 1) * 128 + col]);
}

// ---------- x -> bf16 with rsO pre-scale ----------
__global__ void xconv_kernel(const float4* __restrict__ x, const float* __restrict__ rsO,
                             uint4* __restrict__ xb, int n /* N*16 */) {
    int i = blockIdx.x * blockDim.x + threadIdx.x;
    if (i >= n) return;
    float sc = rsO[i >> 4];
    float4 a = x[i * 2];
    float4 b = x[i * 2 + 1];
    uint4 o;
    o.x = bfpair(a.x * sc, a.y * sc);
    o.y = bfpair(a.z * sc, a.w * sc);
    o.z = bfpair(b.x * sc, b.y * sc);
    o.w = bfpair(b.z * sc, b.w * sc);
    xb[i] = o;
}

// ---------- gather SpMM: out[r] = bf16( rsI[r] * sum_{p in row r} h[eidx[p]] ) ----------
__global__ __launch_bounds__(256) void gather_kernel(
        const int* __restrict__ rowptr, const int* __restrict__ eidx,
        const ushort4* __restrict__ h, const float* __restrict__ rsI,
        uint2* __restrict__ out, int nNodes) {
    int gid = blockIdx.x * blockDim.x + threadIdx.x;
    int r = gid >> 5;
    int q = gid & 31;
    if (r >= nNodes) return;
    int p = rowptr[r], end = rowptr[r + 1];
    float4 accA = make_float4(0.f, 0.f, 0.f, 0.f);
    float4 accB = make_float4(0.f, 0.f, 0.f, 0.f);
    for (; p + 2 <= end; p += 2) {
        ushort4 u0 = h[(size_t)eidx[p] * 32 + q];
        ushort4 u1 = h[(size_t)eidx[p + 1] * 32 + q];
        accA.x += bf2f(u0.x); accA.y += bf2f(u0.y);
        accA.z += bf2f(u0.z); accA.w += bf2f(u0.w);
        accB.x += bf2f(u1.x); accB.y += bf2f(u1.y);
        accB.z += bf2f(u1.z); accB.w += bf2f(u1.w);
    }
    if (p < end) {
        ushort4 u0 = h[(size_t)eidx[p] * 32 + q];
        accA.x += bf2f(u0.x); accA.y += bf2f(u0.y);
        accA.z += bf2f(u0.z); accA.w += bf2f(u0.w);
    }
    float sc = rsI[r];
    uint2 o;
    o.x = bfpair((accA.x + accB.x) * sc, (accA.y + accB.y) * sc);
    o.y = bfpair((accA.z + accB.z) * sc, (accA.w + accB.w) * sc);
    out[(size_t)r * 32 + q] = o;
}

// ---------- MFMA GEMM: o = relu(A@W + b); FUSE0: outb = bf16(o*rsO); FUSE1: acc += sum(o) ----------
// block = 256 thr = 4 waves; wave (wr,wc): rows [ch*32+wr*16,+16) x cols [wc*64,+64)
template <int FUSE>
__global__ __launch_bounds__(256) void gemm_mfma(
        const unsigned short* __restrict__ Ain,   // [N][128] bf16 (rsI-scaled)
        const uint4* __restrict__ Wp,             // packed fragments
        const float* __restrict__ bias, const float* __restrict__ rsO,
        unsigned short* __restrict__ outb, double* __restrict__ acc, int nNodes) {
    const int t = threadIdx.x;
    const int lane = t & 63;
    const int wv = t >> 6;
    const int wr = wv >> 1, wc = wv & 1;
    const int l15 = lane & 15, lh = lane >> 4;

    bf16x8 bfr[4][4];
    #pragma unroll
    for (int kc = 0; kc < 4; ++kc)
        #pragma unroll
        for (int nt = 0; nt < 4; ++nt) {
            uint4 u = Wp[(kc * 8 + wc * 4 + nt) * 64 + lane];
            bfr[kc][nt] = *(bf16x8*)&u;
        }
    float bv[4];
    #pragma unroll
    for (int nt = 0; nt < 4; ++nt) bv[nt] = bias[wc * 64 + nt * 16 + l15];

    double lsum = 0.0;
    const int nChunks = (nNodes + 31) >> 5;
    for (int ch = blockIdx.x; ch < nChunks; ch += gridDim.x) {
        int arow = ch * 32 + wr * 16 + l15;
        if (arow >= nNodes) arow = nNodes - 1;
        const unsigned short* ap = Ain + (size_t)arow * 128 + lh * 8;
        bf16x8 afr[4];
        #pragma unroll
        for (int kc = 0; kc < 4; ++kc) afr[kc] = *(const bf16x8*)(ap + kc * 32);

        f32x4 c[4];
        #pragma unroll
        for (int nt = 0; nt < 4; ++nt) c[nt] = (f32x4){0.f, 0.f, 0.f, 0.f};
        #pragma unroll
        for (int kc = 0; kc < 4; ++kc)
            #pragma unroll
            for (int nt = 0; nt < 4; ++nt)
                c[nt] = __builtin_amdgcn_mfma_f32_16x16x32_bf16(afr[kc], bfr[kc][nt], c[nt], 0, 0, 0);

        int r0 = ch * 32 + wr * 16 + lh * 4;
        if (FUSE) {
            #pragma unroll
            for (int j = 0; j < 4; ++j) {
                if (r0 + j < nNodes) {
                    #pragma unroll
                    for (int nt = 0; nt < 4; ++nt)
                        lsum += (double)fmaxf(c[nt][j] + bv[nt], 0.f);
                }
            }
        } else {
            #pragma unroll
            for (int j = 0; j < 4; ++j) {
                int r = r0 + j;
                if (r < nNodes) {
                    float sc = rsO[r];
                    #pragma unroll
                    for (int nt = 0; nt < 4; ++nt) {
                        float o = fmaxf(c[nt][j] + bv[nt], 0.f) * sc;
                        outb[(size_t)r * 128 + wc * 64 + nt * 16 + l15] = f2bf(o);
                    }
                }
            }
        }
    }

    if (FUSE) {
        for (int off = 32; off; off >>= 1) lsum += __shfl_down(lsum, off, 64);
        __shared__ double wred[4];
        if (lane == 0) wred[wv] = lsum;
        __syncthreads();
        if (t == 0) atomicAdd(acc, wred[0] + wred[1] + wred[2] + wred[3]);
    }
}

__global__ void finalize_kernel(const double* __restrict__ acc, float* __restrict__ out) {
    if (threadIdx.x == 0 && blockIdx.x == 0)
        out[0] = (float)(acc[0] / (4.0 * N_NODES * D));
}

extern "C" void kernel_launch(void* const* d_in, const int* in_sizes, int n_in,
                              void* d_out, int out_size, void* d_ws, size_t ws_size,
                              hipStream_t stream) {
    const float* x[4];
    const int* src[4];
    const int* dst[4];
    for (int g = 0; g < 4; ++g) {
        x[g]   = (const float*)d_in[3 * g + 0];
        src[g] = (const int*)  d_in[3 * g + 1];
        dst[g] = (const int*)  d_in[3 * g + 2];
    }
    const float* W1 = (const float*)d_in[12];
    const float* b1 = (const float*)d_in[13];
    const float* W2 = (const float*)d_in[14];
    const float* b2 = (const float*)d_in[15];
    float* out = (float*)d_out;

    // -------- workspace layout (4-byte units) --------
    // 0     : acc (double)
    // 64    : bCurD[4][64]
    // 320   : bCurS[4][64]
    // 1024  : Wp1 (8192), Wp2 (8192)
    // 17408 : rowptr[4][N+1]  (200004)
    // 217412: rsI[4][N] (200000)
    // 417412: rsO[4][N] (200000)
    // 617412: eidx[4][E] (2400000)
    // 3017412: overlay:  pairs[4][64][BCAP] ints (4194304) + svals (2097152 units)
    //                 OR xbA (3200000) + Ab (3200000) + Bb (3200000)
    // end: 12617412 units = 50.5 MB
    int* ws32 = (int*)d_ws;
    double* acc     = (double*)d_ws;
    int* bCurD      = ws32 + 64;
    int* bCurS      = ws32 + 320;
    unsigned* Wp1   = (unsigned*)(ws32 + 1024);
    unsigned* Wp2   = Wp1 + 8192;
    int* rowptrBase = ws32 + 17408;
    float* rsIBase  = (float*)(ws32 + 217412);
    float* rsOBase  = (float*)(ws32 + 417412);
    int* eixBase    = ws32 + 617412;
    int* pairs      = ws32 + 3017412;
    unsigned short* svals = (unsigned short*)(pairs + 4194304);
    unsigned short* xbA = (unsigned short*)(ws32 + 3017412);
    unsigned short* Ab  = xbA + (size_t)N_NODES * D;
    unsigned short* Bb  = Ab + (size_t)N_NODES * D;

    const int paGrid = (N_EDGES + EPB - 1) / EPB;          // 293
    const int gatherGrid = (N_NODES * 32) / 256;           // 6250
    const int xconvGrid  = (N_NODES * 16 + 255) / 256;     // 3125
    const int gemmGrid   = 782;

    // zero acc + bucket cursors
    hipMemsetAsync(d_ws, 0, 1024 * sizeof(int), stream);

    wconv_kernel<<<dim3(32, 2), 256, 0, stream>>>(W1, W2, Wp1, Wp2);
    phaseA_kernel<<<dim3(paGrid, 4), 256, 0, stream>>>(
        src[0], src[1], src[2], src[3], dst[0], dst[1], dst[2], dst[3],
        bCurD, bCurS, pairs, svals, N_EDGES);
    csrB_kernel<<<dim3(NBUCK, 4), 256, 0, stream>>>(
        bCurD, pairs, rowptrBase, eixBase, rsIBase);
    csrC_kernel<<<dim3(NBUCK, 4), 256, 0, stream>>>(bCurS, svals, rsOBase);

    for (int g = 0; g < 4; ++g) {
        const int* rowptr = rowptrBase + (size_t)g * (N_NODES + 1);
        const int* eidx   = eixBase + (size_t)g * N_EDGES;
        const float* rsI  = rsIBase + (size_t)g * N_NODES;
        const float* rsO  = rsOBase + (size_t)g * N_NODES;

        xconv_kernel<<<xconvGrid, 256, 0, stream>>>(
            (const float4*)x[g], rsO, (uint4*)xbA, N_NODES * 16);
        gather_kernel<<<gatherGrid, 256, 0, stream>>>(
            rowptr, eidx, (const ushort4*)xbA, rsI, (uint2*)Bb, N_NODES);
        gemm_mfma<0><<<gemmGrid, 256, 0, stream>>>(
            Bb, (const uint4*)Wp1, b1, rsO, Ab, nullptr, N_NODES);
        gather_kernel<<<gatherGrid, 256, 0, stream>>>(
            rowptr, eidx, (const ushort4*)Ab, rsI, (uint2*)Bb, N_NODES);
        gemm_mfma<1><<<gemmGrid, 256, 0, stream>>>(
            Bb, (const uint4*)Wp2, b2, nullptr, nullptr, acc, N_NODES);
    }

    finalize_kernel<<<1, 64, 0, stream>>>(acc, out);
}

// Round 7
// 347.978 us; speedup vs baseline: 26.9751x; 1.3595x over previous
//
#include <hip/hip_runtime.h>
#include <hip/hip_bf16.h>

#define N_NODES 50000
#define N_EDGES 600000
#define D 128

#define NBUCK 64
#define BUCK_R 782      // ceil(N/64); 64*782 = 50048
#define BCAP 16384      // per-bucket capacity (mean 9375, std 96)
#define EPB 2048        // edges per phaseA block

typedef __attribute__((ext_vector_type(8))) short bf16x8;
typedef __attribute__((ext_vector_type(4))) float f32x4;

__device__ __forceinline__ const int* pick4(const int* a, const int* b,
                                            const int* c, const int* d, int g) {
    return g == 0 ? a : g == 1 ? b : g == 2 ? c : d;
}
__device__ __forceinline__ const float4* pick4f(const float4* a, const float4* b,
                                                const float4* c, const float4* d, int g) {
    return g == 0 ? a : g == 1 ? b : g == 2 ? c : d;
}

__device__ __forceinline__ unsigned bfpair(float a, float b) {   // RNE pack: lo=a, hi=b
    unsigned ua = __float_as_uint(a); ua = (ua + 0x7FFF + ((ua >> 16) & 1)) >> 16;
    unsigned ub = __float_as_uint(b); ub = (ub + 0x7FFF + ((ub >> 16) & 1)) >> 16;
    return ua | (ub << 16);
}
__device__ __forceinline__ unsigned short f2bf(float x) {
    unsigned u = __float_as_uint(x); u = (u + 0x7FFF + ((u >> 16) & 1)) >> 16;
    return (unsigned short)u;
}

// ---------- phase A: bucket edges by dst (pairs) and by src (svals) ----------
__global__ __launch_bounds__(256) void phaseA_kernel(
        const int* s0, const int* s1, const int* s2, const int* s3,
        const int* d0, const int* d1, const int* d2, const int* d3,
        int* __restrict__ bCurD, int* __restrict__ bCurS,
        int* __restrict__ pairs, unsigned short* __restrict__ svals, int nEdges) {
    int gi = blockIdx.y;
    const int* src = pick4(s0, s1, s2, s3, gi);
    const int* dst = pick4(d0, d1, d2, d3, gi);
    int* pg = pairs + (size_t)gi * NBUCK * BCAP;
    unsigned short* sg = svals + (size_t)gi * NBUCK * BCAP;

    __shared__ int cntD[64], cntS[64], gposD[64], gposS[64], lcurD[64], lcurS[64];
    int t = threadIdx.x;
    if (t < 64) { cntD[t] = 0; cntS[t] = 0; }
    __syncthreads();

    int myD[8], myS[8];
    int base = blockIdx.x * EPB + t;
    #pragma unroll
    for (int j = 0; j < 8; ++j) {
        int e = base + j * 256;
        if (e < nEdges) {
            myD[j] = dst[e]; myS[j] = src[e];
            atomicAdd(&cntD[myD[j] / BUCK_R], 1);
            atomicAdd(&cntS[myS[j] / BUCK_R], 1);
        } else myD[j] = -1;
    }
    __syncthreads();
    if (t < 64) {
        int c = cntD[t];
        gposD[t] = t * BCAP + (c ? atomicAdd(&bCurD[gi * 64 + t], c) : 0);
        lcurD[t] = 0;
        c = cntS[t];
        gposS[t] = t * BCAP + (c ? atomicAdd(&bCurS[gi * 64 + t], c) : 0);
        lcurS[t] = 0;
    }
    __syncthreads();
    #pragma unroll
    for (int j = 0; j < 8; ++j) {
        if (myD[j] >= 0) {
            int bD = myD[j] / BUCK_R, bS = myS[j] / BUCK_R;
            int lp = atomicAdd(&lcurD[bD], 1);
            pg[gposD[bD] + lp] = ((myD[j] - bD * BUCK_R) << 16) | myS[j];
            int ls = atomicAdd(&lcurS[bS], 1);
            sg[gposS[bS] + ls] = (unsigned short)(myS[j] - bS * BUCK_R);
        }
    }
}

// ---------- csrB: per (graph,bucket): LDS hist + scan + scatter -> rowptr/rsI/eidx ----------
__global__ __launch_bounds__(256) void csrB_kernel(
        const int* __restrict__ bCurD, const int* __restrict__ pairs,
        int* __restrict__ rowptrBase, int* __restrict__ eixBase,
        float* __restrict__ rsIBase) {
    int gi = blockIdx.y, b = blockIdx.x;
    int* rowptr = rowptrBase + (size_t)gi * (N_NODES + 1);
    int* eidx = eixBase + (size_t)gi * N_EDGES;
    float* rsI = rsIBase + (size_t)gi * N_NODES;
    const int* pg = pairs + ((size_t)gi * NBUCK + b) * BCAP;
    const int* bCur = bCurD + gi * 64;

    __shared__ int P[BCAP];
    __shared__ int cnt[1024];
    __shared__ int cur[1024];
    __shared__ int wpart[4];
    __shared__ int sbase;

    int t = threadIdx.x;
    int nb = bCur[b]; if (nb > BCAP) nb = BCAP;

    if (t < 64) {
        int v = (t < b) ? min(bCur[t], BCAP) : 0;
        for (int off = 32; off; off >>= 1) v += __shfl_down(v, off, 64);
        if (t == 0) sbase = v;
    }
    for (int i = t; i < 1024; i += 256) cnt[i] = 0;
    __syncthreads();
    int base = sbase;

    for (int i = t; i < nb; i += 256) {
        int p = pg[i];
        P[i] = p;
        atomicAdd(&cnt[p >> 16], 1);
    }
    __syncthreads();

    int c0 = cnt[t * 4 + 0], c1 = cnt[t * 4 + 1], c2 = cnt[t * 4 + 2], c3 = cnt[t * 4 + 3];
    int ts = c0 + c1 + c2 + c3;
    int lane = t & 63, w = t >> 6;
    int incl = ts;
    for (int off = 1; off < 64; off <<= 1) {
        int u = __shfl_up(incl, off, 64);
        if (lane >= off) incl += u;
    }
    if (lane == 63) wpart[w] = incl;
    __syncthreads();
    int wb = 0;
    #pragma unroll
    for (int i = 0; i < 4; ++i) if (i < w) wb += wpart[i];
    int ex = wb + incl - ts;
    cur[t * 4 + 0] = ex;
    cur[t * 4 + 1] = ex + c0;
    cur[t * 4 + 2] = ex + c0 + c1;
    cur[t * 4 + 3] = ex + c0 + c1 + c2;
    __syncthreads();

    int lo = b * BUCK_R;
    int nh = N_NODES - lo; if (nh > BUCK_R) nh = BUCK_R;
    for (int i = t; i < nh; i += 256) {
        rowptr[lo + i] = base + cur[i];
        rsI[lo + i] = 1.0f / sqrtf(fmaxf((float)cnt[i], 1.0f));
    }
    if (b == NBUCK - 1 && t == 0) rowptr[N_NODES] = N_EDGES;
    __syncthreads();

    for (int i = t; i < nb; i += 256) {
        int p = P[i];
        int pos = atomicAdd(&cur[p >> 16], 1);
        eidx[base + pos] = p & 0xFFFF;   // src
    }
}

// ---------- csrC: per (graph,bucket): LDS hist of src -> rsO ----------
__global__ __launch_bounds__(256) void csrC_kernel(
        const int* __restrict__ bCurS, const unsigned short* __restrict__ svals,
        float* __restrict__ rsOBase) {
    int gi = blockIdx.y, b = blockIdx.x;
    float* rsO = rsOBase + (size_t)gi * N_NODES;
    const unsigned short* sg = svals + ((size_t)gi * NBUCK + b) * BCAP;
    __shared__ int cnt[1024];
    int t = threadIdx.x;
    for (int i = t; i < 1024; i += 256) cnt[i] = 0;
    __syncthreads();
    int ns = bCurS[gi * 64 + b]; if (ns > BCAP) ns = BCAP;
    for (int i = t; i < ns; i += 256) atomicAdd(&cnt[sg[i]], 1);
    __syncthreads();
    int lo = b * BUCK_R;
    int nh = N_NODES - lo; if (nh > BUCK_R) nh = BUCK_R;
    for (int i = t; i < nh; i += 256)
        rsO[lo + i] = 1.0f / sqrtf(fmaxf((float)cnt[i], 1.0f));
}

// ---------- W fp32 -> packed bf16 MFMA B-fragment layout ----------
__global__ void wconv_kernel(const float* __restrict__ W1, const float* __restrict__ W2,
                             unsigned* __restrict__ Wp1, unsigned* __restrict__ Wp2) {
    const float* W = blockIdx.y ? W2 : W1;
    unsigned* Wp = blockIdx.y ? Wp2 : Wp1;
    int o = blockIdx.x * 256 + threadIdx.x;      // 0..8191
    int j2 = o & 3, lane = (o >> 2) & 63, nt = (o >> 8) & 7, kc = o >> 11;
    int k = kc * 32 + (lane >> 4) * 8 + j2 * 2;
    int col = nt * 16 + (lane & 15);
    Wp[o] = bfpair(W[k * 128 + col], W[(k + 1) * 128 + col]);
}

// ---------- x -> bf16 with rsO pre-scale (batched over graphs) ----------
__global__ void xconv_kernel(const float4* x0, const float4* x1,
                             const float4* x2, const float4* x3,
                             const float* __restrict__ rsOBase,
                             uint4* __restrict__ xbBase, int gFirst, int n /* N*16 */) {
    int gi = blockIdx.y;
    const float4* x = pick4f(x0, x1, x2, x3, gFirst + gi);
    const float* rsO = rsOBase + (size_t)(gFirst + gi) * N_NODES;
    // FIX (round 6 bug): one graph's bf16 table = N*128 bf16 = N*16 uint4s.
    uint4* xb = xbBase + (size_t)gi * (N_NODES * 16);
    int i = blockIdx.x * blockDim.x + threadIdx.x;
    if (i >= n) return;
    float sc = rsO[i >> 4];
    float4 a = x[i * 2];
    float4 b = x[i * 2 + 1];
    uint4 o;
    o.x = bfpair(a.x * sc, a.y * sc);
    o.y = bfpair(a.z * sc, a.w * sc);
    o.z = bfpair(b.x * sc, b.y * sc);
    o.w = bfpair(b.z * sc, b.w * sc);
    xb[i] = o;
}

// ---------- fused gather + MFMA GEMM ----------
// Per 16-row chunk: 16 thr/row gather h[eidx[p]] (bf16) into f32 regs, scale by
// rsI, pack bf16 to LDS A; then 4 waves compute A(16x128) @ W(128x128) via MFMA.
// LAYER 1: out[r][c] = bf16(relu(.+b)*rsO[r]);  LAYER 2: acc += sum(relu(.+b))
#define NCHUNK 3125   // 50000/16
template <int LAYER>
__global__ __launch_bounds__(256) void fused_kernel(
        const int* __restrict__ rowptrBase, const int* __restrict__ eixBase,
        const unsigned short* __restrict__ hBase,     // [gi][N*128] bf16
        const float* __restrict__ rsIBase, const float* __restrict__ rsOBase,
        const uint4* __restrict__ Wp, const float* __restrict__ bias,
        unsigned short* __restrict__ outBase, double* __restrict__ acc, int gFirst) {
    const int gi = blockIdx.y;
    const int g = gFirst + gi;
    const int* rowptr = rowptrBase + (size_t)g * (N_NODES + 1);
    const int* eidx   = eixBase + (size_t)g * N_EDGES;
    const float* rsI  = rsIBase + (size_t)g * N_NODES;
    const float* rsO  = rsOBase + (size_t)g * N_NODES;
    const unsigned short* h = hBase + (size_t)gi * N_NODES * D;
    unsigned short* outb = outBase + (size_t)gi * N_NODES * D;

    __shared__ unsigned short A[16][136];    // padded stride

    const int t = threadIdx.x;
    const int row = t >> 4;          // 0..15
    const int sub = t & 15;          // 8-col slice
    const int lane = t & 63, wv = t >> 6;
    const int l15 = lane & 15, lh = lane >> 4;

    // W fragments: register-resident across grid-stride chunks
    bf16x8 bfr[4][2];
    #pragma unroll
    for (int kc = 0; kc < 4; ++kc)
        #pragma unroll
        for (int j = 0; j < 2; ++j) {
            uint4 u = Wp[(kc * 8 + wv * 2 + j) * 64 + lane];
            bfr[kc][j] = *(bf16x8*)&u;
        }
    float bv[2];
    #pragma unroll
    for (int j = 0; j < 2; ++j) bv[j] = bias[wv * 32 + j * 16 + l15];

    double lsum = 0.0;

    for (int ch = blockIdx.x; ch < NCHUNK; ch += gridDim.x) {
        const int r = ch * 16 + row;
        // ---- gather phase ----
        float a[8] = {0.f, 0.f, 0.f, 0.f, 0.f, 0.f, 0.f, 0.f};
        int p = rowptr[r], pend = rowptr[r + 1];
        const unsigned short* hp = h + sub * 8;
        for (; p + 2 <= pend; p += 2) {
            uint4 u = *(const uint4*)(hp + (size_t)eidx[p] * 128);
            uint4 v = *(const uint4*)(hp + (size_t)eidx[p + 1] * 128);
            a[0] += __uint_as_float(u.x << 16);  a[1] += __uint_as_float(u.x & 0xFFFF0000u);
            a[2] += __uint_as_float(u.y << 16);  a[3] += __uint_as_float(u.y & 0xFFFF0000u);
            a[4] += __uint_as_float(u.z << 16);  a[5] += __uint_as_float(u.z & 0xFFFF0000u);
            a[6] += __uint_as_float(u.w << 16);  a[7] += __uint_as_float(u.w & 0xFFFF0000u);
            a[0] += __uint_as_float(v.x << 16);  a[1] += __uint_as_float(v.x & 0xFFFF0000u);
            a[2] += __uint_as_float(v.y << 16);  a[3] += __uint_as_float(v.y & 0xFFFF0000u);
            a[4] += __uint_as_float(v.z << 16);  a[5] += __uint_as_float(v.z & 0xFFFF0000u);
            a[6] += __uint_as_float(v.w << 16);  a[7] += __uint_as_float(v.w & 0xFFFF0000u);
        }
        if (p < pend) {
            uint4 u = *(const uint4*)(hp + (size_t)eidx[p] * 128);
            a[0] += __uint_as_float(u.x << 16);  a[1] += __uint_as_float(u.x & 0xFFFF0000u);
            a[2] += __uint_as_float(u.y << 16);  a[3] += __uint_as_float(u.y & 0xFFFF0000u);
            a[4] += __uint_as_float(u.z << 16);  a[5] += __uint_as_float(u.z & 0xFFFF0000u);
            a[6] += __uint_as_float(u.w << 16);  a[7] += __uint_as_float(u.w & 0xFFFF0000u);
        }
        {
            float sc = rsI[r];
            uint4 pk;
            pk.x = bfpair(a[0] * sc, a[1] * sc);
            pk.y = bfpair(a[2] * sc, a[3] * sc);
            pk.z = bfpair(a[4] * sc, a[5] * sc);
            pk.w = bfpair(a[6] * sc, a[7] * sc);
            *(uint4*)&A[row][sub * 8] = pk;
        }
        __syncthreads();

        // ---- MFMA phase ----
        bf16x8 afr[4];
        #pragma unroll
        for (int kc = 0; kc < 4; ++kc) {
            uint4 u = *(const uint4*)&A[l15][kc * 32 + lh * 8];
            afr[kc] = *(bf16x8*)&u;
        }
        __syncthreads();    // A consumed; next gather may overwrite

        f32x4 c[2];
        c[0] = (f32x4){0.f, 0.f, 0.f, 0.f};
        c[1] = (f32x4){0.f, 0.f, 0.f, 0.f};
        #pragma unroll
        for (int kc = 0; kc < 4; ++kc) {
            c[0] = __builtin_amdgcn_mfma_f32_16x16x32_bf16(afr[kc], bfr[kc][0], c[0], 0, 0, 0);
            c[1] = __builtin_amdgcn_mfma_f32_16x16x32_bf16(afr[kc], bfr[kc][1], c[1], 0, 0, 0);
        }

        const int r0 = ch * 16 + lh * 4;
        if (LAYER == 2) {
            #pragma unroll
            for (int jj = 0; jj < 4; ++jj) {
                lsum += (double)fmaxf(c[0][jj] + bv[0], 0.f)
                      + (double)fmaxf(c[1][jj] + bv[1], 0.f);
            }
        } else {
            #pragma unroll
            for (int jj = 0; jj < 4; ++jj) {
                float sc = rsO[r0 + jj];
                outb[(size_t)(r0 + jj) * 128 + wv * 32 + l15]      = f2bf(fmaxf(c[0][jj] + bv[0], 0.f) * sc);
                outb[(size_t)(r0 + jj) * 128 + wv * 32 + 16 + l15] = f2bf(fmaxf(c[1][jj] + bv[1], 0.f) * sc);
            }
        }
    }

    if (LAYER == 2) {
        for (int off = 32; off; off >>= 1) lsum += __shfl_down(lsum, off, 64);
        __shared__ double wred[4];
        if (lane == 0) wred[wv] = lsum;
        __syncthreads();
        if (t == 0) atomicAdd(acc, wred[0] + wred[1] + wred[2] + wred[3]);
    }
}

__global__ void finalize_kernel(const double* __restrict__ acc, float* __restrict__ out) {
    if (threadIdx.x == 0 && blockIdx.x == 0)
        out[0] = (float)(acc[0] / (4.0 * N_NODES * D));
}

extern "C" void kernel_launch(void* const* d_in, const int* in_sizes, int n_in,
                              void* d_out, int out_size, void* d_ws, size_t ws_size,
                              hipStream_t stream) {
    const float* x[4];
    const int* src[4];
    const int* dst[4];
    for (int g = 0; g < 4; ++g) {
        x[g]   = (const float*)d_in[3 * g + 0];
        src[g] = (const int*)  d_in[3 * g + 1];
        dst[g] = (const int*)  d_in[3 * g + 2];
    }
    const float* W1 = (const float*)d_in[12];
    const float* b1 = (const float*)d_in[13];
    const float* W2 = (const float*)d_in[14];
    const float* b2 = (const float*)d_in[15];
    float* out = (float*)d_out;

    // -------- workspace layout (4-byte units) --------
    // 0       acc | 64 bCurD[4][64] | 320 bCurS[4][64] | 1024 Wp1+Wp2 (16384)
    // 17408   rowptr[4][N+1] (200004)
    // 217412  rsI[4][N] (200000)
    // 417412  rsO[4][N] (200000)
    // 617412  eidx[4][E] (2400000)
    // 3017412 overlay: pairs(4194304)+svals(2097152)  OR  xb[gb]+Ab[gb] (gb*2*3200000)
    int* ws32 = (int*)d_ws;
    double* acc     = (double*)d_ws;
    int* bCurD      = ws32 + 64;
    int* bCurS      = ws32 + 320;
    unsigned* Wp1   = (unsigned*)(ws32 + 1024);
    unsigned* Wp2   = Wp1 + 8192;
    int* rowptrBase = ws32 + 17408;
    float* rsIBase  = (float*)(ws32 + 217412);
    float* rsOBase  = (float*)(ws32 + 417412);
    int* eixBase    = ws32 + 617412;
    int* pairs      = ws32 + 3017412;
    unsigned short* svals = (unsigned short*)(pairs + 4194304);
    unsigned short* xbA   = (unsigned short*)(ws32 + 3017412);

    // pick sub-batch size by available workspace
    auto needBytes = [](int gb) -> size_t {
        size_t ov = (size_t)gb * 6400000;   // xb + Ab per graph, in 4B units
        if (ov < 6291456) ov = 6291456;     // at least pairs+svals overlay
        return (3017412 + ov) * 4;
    };
    int gb = 1;
    if (ws_size >= needBytes(4)) gb = 4;
    else if (ws_size >= needBytes(2)) gb = 2;
    unsigned short* AbA = xbA + (size_t)gb * N_NODES * D;

    const int paGrid    = (N_EDGES + EPB - 1) / EPB;       // 293
    const int xconvGrid = (N_NODES * 16 + 255) / 256;      // 3125
    const int fusedGrid = 1563;                            // ~2 chunks/block

    hipMemsetAsync(d_ws, 0, 1024 * sizeof(int), stream);

    wconv_kernel<<<dim3(32, 2), 256, 0, stream>>>(W1, W2, Wp1, Wp2);
    phaseA_kernel<<<dim3(paGrid, 4), 256, 0, stream>>>(
        src[0], src[1], src[2], src[3], dst[0], dst[1], dst[2], dst[3],
        bCurD, bCurS, pairs, svals, N_EDGES);
    csrB_kernel<<<dim3(NBUCK, 4), 256, 0, stream>>>(
        bCurD, pairs, rowptrBase, eixBase, rsIBase);
    csrC_kernel<<<dim3(NBUCK, 4), 256, 0, stream>>>(bCurS, svals, rsOBase);

    for (int g0 = 0; g0 < 4; g0 += gb) {
        int nb = 4 - g0 < gb ? 4 - g0 : gb;
        xconv_kernel<<<dim3(xconvGrid, nb), 256, 0, stream>>>(
            (const float4*)x[0], (const float4*)x[1], (const float4*)x[2], (const float4*)x[3],
            rsOBase, (uint4*)xbA, g0, N_NODES * 16);
        fused_kernel<1><<<dim3(fusedGrid, nb), 256, 0, stream>>>(
            rowptrBase, eixBase, xbA, rsIBase, rsOBase,
            (const uint4*)Wp1, b1, AbA, nullptr, g0);
        fused_kernel<2><<<dim3(fusedGrid, nb), 256, 0, stream>>>(
            rowptrBase, eixBase, AbA, rsIBase, rsOBase,
            (const uint4*)Wp2, b2, nullptr, acc, g0);
    }

    finalize_kernel<<<1, 64, 0, stream>>>(acc, out);
}